// Round 7
// baseline (657.508 us; speedup 1.0000x reference)
//
#include <hip/hip_runtime.h>

// ---------------- problem dims ----------------
constexpr int NB = 16;    // batch
constexpr int CC = 32;    // in channels
constexpr int VV = 2048;  // fine nodes
constexpr int VCC = 256;  // coarse nodes
constexpr int SS = 64;    // super nodes
constexpr int LL = 12;    // time
constexpr int CO = 32;    // out channels
constexpr long MM = (long)NB * CO * LL;  // 6144 rows in node-last layout

typedef __attribute__((ext_vector_type(8))) __bf16 bf16x8;
typedef __attribute__((ext_vector_type(4))) float f32x4;

__device__ __forceinline__ unsigned short f2bf(float f) {
    unsigned u = __float_as_uint(f);
    unsigned r = u + 0x7FFFu + ((u >> 16) & 1u);  // RNE
    return (unsigned short)(r >> 16);
}

__device__ __forceinline__ void gl_lds16(const void* g, void* l) {
    __builtin_amdgcn_global_load_lds(
        (const __attribute__((address_space(1))) void*)g,
        (__attribute__((address_space(3))) void*)l, 16, 0, 0);
}

// =====================================================================
// K1 (slim): x [nc, V, 12] -> xtb bf16 [nc, 12, V] ONLY (fp32 xt copy
// eliminated -- chanmix_fuse now reads x directly). 13-pad LDS rows.
__global__ __launch_bounds__(256)
void transpose_vb(const float* __restrict__ in, unsigned short* __restrict__ outb) {
    __shared__ float t[128 * 13];
    const long nc = blockIdx.y;
    const int v0 = blockIdx.x * 128;
    const float* src = in + (nc * VV + v0) * 12;
    for (int f = threadIdx.x; f < 128 * 12; f += 256) {
        const int vv = f / 12, l = f - vv * 12;
        t[vv * 13 + l] = src[f];
    }
    __syncthreads();
    unsigned short* dstb = outb + nc * 12L * VV;
    for (int g = threadIdx.x; g < 128 * 12; g += 256) {
        int l = g >> 7, vv = g & 127;
        dstb[(long)l * VV + v0 + vv] = f2bf(t[vv * 13 + l]);
    }
}

// out-transpose: in [nc, 12, Kn] -> out [nc, Kn, 12]  (13-pad)
__global__ __launch_bounds__(256)
void transpose_lv(const float* __restrict__ in, float* __restrict__ out, int Kn, int TW) {
    __shared__ float t[128 * 13];
    const long nc = blockIdx.y;
    const int v0 = blockIdx.x * TW;
    const float* src = in + nc * 12L * Kn;
    for (int g = threadIdx.x; g < TW * 12; g += 256) {
        int l = g / TW, vv = g - l * TW;
        t[vv * 13 + l] = src[(long)l * Kn + v0 + vv];
    }
    __syncthreads();
    float* dst = out + (nc * Kn + v0) * 12L;
    for (int f = threadIdx.x; f < TW * 12; f += 256) {
        const int vv = f / 12, l = f - vv * 12;
        dst[f] = t[vv * 13 + l];
    }
}

// small dense fp32 transpose: in [rows, cols] -> out [cols, rows]
__global__ __launch_bounds__(256)
void transpose2d(const float* __restrict__ in, float* __restrict__ out, int rows, int cols) {
    __shared__ float t[32][33];
    const int r0 = blockIdx.y * 32, c0 = blockIdx.x * 32;
    const int ty = threadIdx.x / 32, tx = threadIdx.x % 32;
    for (int i = ty; i < 32; i += 8) t[i][tx] = in[(long)(r0 + i) * cols + c0 + tx];
    __syncthreads();
    for (int i = ty; i < 32; i += 8) out[(long)(c0 + i) * rows + r0 + tx] = t[tx][i];
}

// fp32 [R,C] -> bf16 transpose [C,R]
__global__ __launch_bounds__(256)
void cvt_T_bf16_k(const float* __restrict__ in, unsigned short* __restrict__ out,
                  int R, int Ccols) {
    __shared__ float t[32][33];
    const int r0 = blockIdx.y * 32, c0 = blockIdx.x * 32;
    const int ty = threadIdx.x / 32, tx = threadIdx.x % 32;
    for (int i = ty; i < 32; i += 8) t[i][tx] = in[(long)(r0 + i) * Ccols + c0 + tx];
    __syncthreads();
    for (int i = ty; i < 32; i += 8) out[(long)(c0 + i) * R + r0 + tx] = f2bf(t[tx][i]);
}

// afc [2048,256] fp32 -> afcb bf16 [2048,256] AND afcTb bf16 [256,2048]
__global__ __launch_bounds__(256)
void cvt_afc_both(const float* __restrict__ in, unsigned short* __restrict__ outn,
                  unsigned short* __restrict__ outt) {
    __shared__ float t[32][33];
    const int r0 = blockIdx.y * 32, c0 = blockIdx.x * 32;
    const int ty = threadIdx.x / 32, tx = threadIdx.x % 32;
    for (int i = ty; i < 32; i += 8) {
        const float v = in[(long)(r0 + i) * VCC + c0 + tx];
        t[i][tx] = v;
        outn[(long)(r0 + i) * VCC + c0 + tx] = f2bf(v);
    }
    __syncthreads();
    for (int i = ty; i < 32; i += 8)
        outt[(long)(c0 + i) * VV + r0 + tx] = f2bf(t[tx][i]);
}

// =====================================================================
// fused fine channel mix: reads x [nb, c, V, 12] DIRECTLY (coalesced 3 KB
// slabs per (nb,c)), transposes in LDS (13-pad -> conflict-free stride-13
// reads), computes y0 fp32 [M,2048] + y12 bf16 [M,4096]. Eliminates the
// 100 MB xt fp32 write+read round-trip of the old transpose_vl+chanmix
// pair. FMA order (c ascending) identical -> bit-identical outputs.
// LDS: 32c x (64v x 13) fp32 = 104 KiB + Ws 12 KiB -> 1 block/CU.
__global__ __launch_bounds__(256)
void chanmix_fuse(const float* __restrict__ x, const float* __restrict__ Wt,
                  float* __restrict__ y0, unsigned short* __restrict__ y12) {
    __shared__ float xs[32 * 832];   // (c, vl*13 + l)
    __shared__ float Ws[CO * 96];
    const int tid = threadIdx.x;
    const int nb = blockIdx.y;
    const int v0 = blockIdx.x * 64;
    for (int i = tid; i < CO * 96; i += 256) Ws[i] = Wt[i];
    // load 32 slabs of 768 contiguous floats (192 float4 each), coalesced
    for (int i = tid; i < 32 * 192; i += 256) {
        const int c = i / 192, q = i - c * 192;
        const float4 v = *(const float4*)(x + ((long)(nb * CC + c) * VV + v0) * 12 + q * 4);
        const float vv[4] = {v.x, v.y, v.z, v.w};
#pragma unroll
        for (int j = 0; j < 4; ++j) {
            const int f = q * 4 + j;
            const int vl = f / 12, l = f - vl * 12;
            xs[c * 832 + vl * 13 + l] = vv[j];
        }
    }
    __syncthreads();
#pragma unroll
    for (int pp = 0; pp < 3; ++pp) {
        const int p = pp * 256 + tid;            // 0..767 = l*64 + vl
        const int l = p >> 6, vl = p & 63;
        float xv[CC];
#pragma unroll
        for (int c = 0; c < CC; ++c) xv[c] = xs[c * 832 + vl * 13 + l];
        const int k = v0 + vl;
        for (int o = 0; o < CO; ++o) {
            float a0 = 0.f, a1 = 0.f, a2 = 0.f;
#pragma unroll
            for (int c = 0; c < CC; ++c) {
                const float xx = xv[c];
                a0 = fmaf(Ws[o * 96 + c], xx, a0);
                a1 = fmaf(Ws[o * 96 + 32 + c], xx, a1);
                a2 = fmaf(Ws[o * 96 + 64 + c], xx, a2);
            }
            const long mrow = (long)(nb * CO + o) * LL + l;
            y0[mrow * VV + k] = a0;
            y12[mrow * 4096 + k] = f2bf(a1);
            y12[mrow * 4096 + 2048 + k] = f2bf(a2);
        }
    }
}

// coarse/super channel mix (fp32 outputs)
__global__ __launch_bounds__(256)
void chanmix_k(const float* __restrict__ in, const float* __restrict__ Wt,
               int R, int Kn, float* __restrict__ o0,
               float* __restrict__ o1, int ld1) {
    __shared__ float Ws[CO * 96];
    for (int idx = threadIdx.x; idx < CO * 96; idx += 256) Ws[idx] = Wt[idx];
    __syncthreads();
    const int nb = blockIdx.y;
    const int r = blockIdx.x * 256 + threadIdx.x;
    if (r >= R) return;
    const int l = r / Kn, k = r - l * Kn;
    float xv[CC];
#pragma unroll
    for (int c = 0; c < CC; ++c) xv[c] = in[((long)(nb * CC + c)) * R + r];
    for (int o = 0; o < CO; ++o) {
        float a0 = 0.f, a1 = 0.f, a2 = 0.f;
#pragma unroll
        for (int c = 0; c < CC; ++c) {
            const float x = xv[c];
            a0 = fmaf(Ws[o * 96 + c], x, a0);
            a1 = fmaf(Ws[o * 96 + 32 + c], x, a1);
            a2 = fmaf(Ws[o * 96 + 64 + c], x, a2);
        }
        const long mrow = (long)(nb * CO + o) * LL + l;
        o0[mrow * Kn + k] = a0;
        o1[mrow * ld1 + k] = a1;
        o1[mrow * ld1 + Kn + k] = a2;
    }
}

// =====================================================================
// bf16 MFMA GEMM: Out[m,n] = (ADDC0? C0[m,n]:0) + (BIAS? bias[(m/12)&31]:0)
//                           + alpha * (RELU? relu(A@B) : A@B)
// A [M,K] bf16 (lda), Bt [N,K] bf16 (ldb) (= B^T). Tile 128xBN, BK=64,
// 4 waves, 16x16x32 MFMA, XOR-swizzled LDS, global_load_lds width-16.
template <int BN, bool SWIZ, bool RELU, bool ADDC0, bool BIAS, bool STB16>
__global__ __launch_bounds__(256)
void gemm_mfma(const unsigned short* __restrict__ A, int lda,
               const unsigned short* __restrict__ Bt, int ldb,
               const float* __restrict__ C0, int ldc,
               const float* __restrict__ bias,
               float* __restrict__ Out, int ldo,
               unsigned short* __restrict__ OutB, int K, float alpha) {
    constexpr int TNT = BN / 32;   // 16-tiles per wave along n (4 or 2)
    constexpr int QB = BN / 32;    // B staging iters (4 or 2)
    constexpr int WN = BN / 2;     // wave n-extent
    __shared__ __align__(16) unsigned short As[128 * 64];
    __shared__ __align__(16) unsigned short Bs[BN * 64];
    const int tid = threadIdx.x;
    const int lane = tid & 63;
    const int w = tid >> 6;

    int pid_m, pid_n;
    if constexpr (SWIZ) {
        const int id = blockIdx.y * gridDim.x + blockIdx.x;
        const int npg = 8 * gridDim.x;
        const int rem = id % npg;
        pid_m = (id / npg) * 8 + (rem & 7);
        pid_n = rem >> 3;
    } else {
        pid_m = blockIdx.y;
        pid_n = blockIdx.x;
    }
    const long m0 = (long)pid_m * 128;
    const int n0 = pid_n * BN;

    long offA[4], offB[QB];
#pragma unroll
    for (int q = 0; q < 4; ++q) {
        const int t = q * 256 + tid;
        const int row = t >> 3, pos = t & 7;
        const int lc = pos ^ (row & 7);
        offA[q] = (m0 + row) * (long)lda + lc * 8;
    }
#pragma unroll
    for (int q = 0; q < QB; ++q) {
        const int t = q * 256 + tid;
        const int row = t >> 3, pos = t & 7;
        const int lc = pos ^ (row & 7);
        offB[q] = (long)(n0 + row) * ldb + lc * 8;
    }
    const int wm = (w & 1) * 64, wn = (w >> 1) * WN;
    const int mrow = lane & 15;
    const int quad = lane >> 4;

    f32x4 acc[4][TNT];
#pragma unroll
    for (int i = 0; i < 4; ++i)
#pragma unroll
        for (int j = 0; j < TNT; ++j) acc[i][j] = (f32x4){0.f, 0.f, 0.f, 0.f};

    for (int k0 = 0; k0 < K; k0 += 64) {
#pragma unroll
        for (int q = 0; q < 4; ++q)
            gl_lds16(A + offA[q] + k0, &As[(q * 256 + w * 64) * 8]);
#pragma unroll
        for (int q = 0; q < QB; ++q)
            gl_lds16(Bt + offB[q] + k0, &Bs[(q * 256 + w * 64) * 8]);
        __syncthreads();
#pragma unroll
        for (int ks = 0; ks < 2; ++ks) {
            bf16x8 af[4], bfr[TNT];
            const int pos = (ks * 4 + quad) ^ (mrow & 7);
#pragma unroll
            for (int tm = 0; tm < 4; ++tm) {
                const int r = wm + tm * 16 + mrow;
                af[tm] = *(const bf16x8*)&As[r * 64 + pos * 8];
            }
#pragma unroll
            for (int tn = 0; tn < TNT; ++tn) {
                const int r = wn + tn * 16 + mrow;
                bfr[tn] = *(const bf16x8*)&Bs[r * 64 + pos * 8];
            }
#pragma unroll
            for (int tm = 0; tm < 4; ++tm)
#pragma unroll
                for (int tn = 0; tn < TNT; ++tn)
                    acc[tm][tn] = __builtin_amdgcn_mfma_f32_16x16x32_bf16(
                        af[tm], bfr[tn], acc[tm][tn], 0, 0, 0);
        }
        __syncthreads();
    }

    // C/D layout: col = lane&15, row = quad*4 + reg
#pragma unroll
    for (int tm = 0; tm < 4; ++tm) {
#pragma unroll
        for (int tn = 0; tn < TNT; ++tn) {
            const int n = n0 + wn + tn * 16 + mrow;
#pragma unroll
            for (int reg = 0; reg < 4; ++reg) {
                const long m = m0 + wm + tm * 16 + quad * 4 + reg;
                float p = acc[tm][tn][reg];
                if (RELU) p = fmaxf(p, 0.f);
                p *= alpha;
                float c = 0.f;
                if constexpr (ADDC0) c = C0[m * (long)ldc + n];
                if (BIAS) c += bias[(int)((m / LL) & (CO - 1))];
                const float res = c + p;
                Out[m * (long)ldo + n] = res;
                if constexpr (STB16) OutB[m * (long)ldo + n] = f2bf(res);
            }
        }
    }
}

// =====================================================================
// 192x256-tile, 8-wave, counted-vmcnt bf16 MFMA GEMM (VERIFIED round-3
// schedule: 108 us, MfmaUtil 40%). Round-5's 4-phase fine-gated variant
// REGRESSED (142 us, m141/m196 order-pinning) -- keep this structure.
// Grid (8,32) = 256 blocks = exact 1-block/CU fill.
__global__ __launch_bounds__(512)
void gemm_mfma256(const unsigned short* __restrict__ A, int lda,
                  const unsigned short* __restrict__ Bt, int ldb,
                  const float* __restrict__ C0, int ldc,
                  const float* __restrict__ bias,
                  float* __restrict__ Out, int ldo, int K) {
    __shared__ __align__(16) unsigned short As[2][192 * 64];
    __shared__ __align__(16) unsigned short Bs[2][256 * 64];
    const int tid = threadIdx.x;
    const int lane = tid & 63;
    const int w = tid >> 6;          // wave 0..7
    const int wr = w >> 2;           // 0..1 : M half (rows wr*96..+95)
    const int wc = w & 3;            // 0..3 : N quarter (cols wc*64..+63)
    const int mrow = lane & 15;
    const int quad = lane >> 4;

    const long m0 = (long)blockIdx.y * 192;
    const int n0 = blockIdx.x * 256;

    long offA[3], offB[4];
#pragma unroll
    for (int q = 0; q < 3; ++q) {
        const int t = q * 512 + tid;
        const int row = t >> 3, pos = t & 7;
        const int lc = pos ^ (row & 7);
        offA[q] = (m0 + row) * (long)lda + lc * 8;
    }
#pragma unroll
    for (int q = 0; q < 4; ++q) {
        const int t = q * 512 + tid;
        const int row = t >> 3, pos = t & 7;
        const int lc = pos ^ (row & 7);
        offB[q] = (long)(n0 + row) * ldb + lc * 8;
    }
    const int NT = K >> 6;

#define STAGE_A(b_, t_)                                                      \
    do {                                                                     \
        gl_lds16(A + offA[0] + (long)(t_) * 64, &As[b_][w * 512]);           \
        gl_lds16(A + offA[1] + (long)(t_) * 64, &As[b_][4096 + w * 512]);    \
        gl_lds16(A + offA[2] + (long)(t_) * 64, &As[b_][8192 + w * 512]);    \
    } while (0)
#define STAGE_B_LO(b_, t_)                                                   \
    do {                                                                     \
        gl_lds16(Bt + offB[0] + (long)(t_) * 64, &Bs[b_][w * 512]);          \
        gl_lds16(Bt + offB[1] + (long)(t_) * 64, &Bs[b_][4096 + w * 512]);   \
    } while (0)
#define STAGE_B_HI(b_, t_)                                                   \
    do {                                                                     \
        gl_lds16(Bt + offB[2] + (long)(t_) * 64, &Bs[b_][8192 + w * 512]);   \
        gl_lds16(Bt + offB[3] + (long)(t_) * 64, &Bs[b_][12288 + w * 512]);  \
    } while (0)

    const int p0 = (quad ^ (mrow & 7)) * 8;           // ks0 chunk
    const int p1 = ((4 + quad) ^ (mrow & 7)) * 8;     // ks1 chunk
    const int ra = (wr * 96 + mrow) * 64;             // + tm*1024
    const int rb = (wc * 64 + mrow) * 64;             // + tn*1024

    f32x4 acc[6][4];
#pragma unroll
    for (int i = 0; i < 6; ++i)
#pragma unroll
        for (int j = 0; j < 4; ++j) acc[i][j] = (f32x4){0.f, 0.f, 0.f, 0.f};

    // prologue: tile0 fully (7 wave-loads), tile1 A + B-lo (5 wave-loads)
    STAGE_A(0, 0); STAGE_B_LO(0, 0); STAGE_B_HI(0, 0);
    if (NT > 1) {
        STAGE_A(1, 1); STAGE_B_LO(1, 1);
        asm volatile("s_waitcnt vmcnt(5)" ::: "memory");  // tile0 landed
    } else {
        asm volatile("s_waitcnt vmcnt(0)" ::: "memory");
    }
    __builtin_amdgcn_sched_barrier(0);
    __builtin_amdgcn_s_barrier();
    __builtin_amdgcn_sched_barrier(0);

    for (int t = 0; t < NT; ++t) {
        const int buf = t & 1;
        bf16x8 a0[6], b0[4], a1[6], b1[4];
#pragma unroll
        for (int tm = 0; tm < 6; ++tm)
            a0[tm] = *(const bf16x8*)&As[buf][ra + tm * 1024 + p0];
#pragma unroll
        for (int tn = 0; tn < 4; ++tn)
            b0[tn] = *(const bf16x8*)&Bs[buf][rb + tn * 1024 + p0];
        if (t + 1 < NT) { STAGE_B_HI(buf ^ 1, t + 1); }  // other buffer: safe
        __builtin_amdgcn_s_setprio(1);
#pragma unroll
        for (int tm = 0; tm < 6; ++tm)
#pragma unroll
            for (int tn = 0; tn < 4; ++tn)
                acc[tm][tn] = __builtin_amdgcn_mfma_f32_16x16x32_bf16(
                    a0[tm], b0[tn], acc[tm][tn], 0, 0, 0);
        __builtin_amdgcn_s_setprio(0);
#pragma unroll
        for (int tm = 0; tm < 6; ++tm)
            a1[tm] = *(const bf16x8*)&As[buf][ra + tm * 1024 + p1];
#pragma unroll
        for (int tn = 0; tn < 4; ++tn)
            b1[tn] = *(const bf16x8*)&Bs[buf][rb + tn * 1024 + p1];
        asm volatile("s_waitcnt lgkmcnt(0)" ::: "memory");  // drain buf reads
        __builtin_amdgcn_sched_barrier(0);
        __builtin_amdgcn_s_barrier();
        __builtin_amdgcn_sched_barrier(0);
        // all waves' reads of buf done -> safe to overwrite with tile t+2
        if (t + 2 < NT) { STAGE_A(buf, t + 2); STAGE_B_LO(buf, t + 2); }
        __builtin_amdgcn_s_setprio(1);
#pragma unroll
        for (int tm = 0; tm < 6; ++tm)
#pragma unroll
            for (int tn = 0; tn < 4; ++tn)
                acc[tm][tn] = __builtin_amdgcn_mfma_f32_16x16x32_bf16(
                    a1[tm], b1[tn], acc[tm][tn], 0, 0, 0);
        __builtin_amdgcn_s_setprio(0);
        if (t + 2 < NT) {
            asm volatile("s_waitcnt vmcnt(5)" ::: "memory");  // tile t+1 landed
        } else if (t + 1 < NT) {
            asm volatile("s_waitcnt vmcnt(0)" ::: "memory");  // tail drain
        }
        __builtin_amdgcn_sched_barrier(0);
        __builtin_amdgcn_s_barrier();
        __builtin_amdgcn_sched_barrier(0);
    }
#undef STAGE_A
#undef STAGE_B_LO
#undef STAGE_B_HI

    // epilogue: C/D layout col = lane&15, row = quad*4 + reg
#pragma unroll
    for (int tm = 0; tm < 6; ++tm) {
#pragma unroll
        for (int tn = 0; tn < 4; ++tn) {
            const int n = n0 + wc * 64 + tn * 16 + mrow;
#pragma unroll
            for (int reg = 0; reg < 4; ++reg) {
                const long m = m0 + wr * 96 + tm * 16 + quad * 4 + reg;
                float p = acc[tm][tn][reg];
                float c = C0[m * (long)ldc + n];
                c += bias[(int)((m / LL) & (CO - 1))];
                Out[m * (long)ldo + n] = c + p;
            }
        }
    }
}

// =====================================================================
// generic fp32 GEMM (narrow / accuracy-critical ops); optional bf16 dual store
template <int BM, int BN, int BK, int TM, int TN, bool RELU, bool ADDC0, bool BIAS, bool STB16>
__global__ __launch_bounds__(256)
void gemm_k(const float* __restrict__ X, int ldx,
            const float* __restrict__ Bm, int ldb,
            const float* __restrict__ C0, int ldc,
            const float* __restrict__ bias,
            float* __restrict__ Out, int ldo,
            unsigned short* __restrict__ outb, int K, float alpha) {
    constexpr int TX = BN / TN;
    constexpr int LX = (BM * BK) / 256;
    constexpr int LB = (BN * BK) / 256;
    __shared__ float Xs[BK][BM + 4];
    __shared__ float Bs[BK][BN + 4];
    const int tid = threadIdx.x;
    const int tx = tid % TX, ty = tid / TX;
    const long m0 = (long)blockIdx.y * BM;
    const int n0 = blockIdx.x * BN;
    const int xr = tid / (BK / LX);
    const int xcc = (tid % (BK / LX)) * LX;
    const int br = tid / (BN / LB);
    const int bc = (tid % (BN / LB)) * LB;

    float acc[TM][TN];
#pragma unroll
    for (int i = 0; i < TM; ++i)
#pragma unroll
        for (int j = 0; j < TN; ++j) acc[i][j] = 0.f;

    const float* Xp = X + (m0 + xr) * (long)ldx + xcc;
    const float* Bp = Bm + (long)br * ldb + n0 + bc;

    for (int k0 = 0; k0 < K; k0 += BK) {
        if constexpr (LX == 4) {
            const float4 v = *(const float4*)Xp;
            Xs[xcc + 0][xr] = v.x; Xs[xcc + 1][xr] = v.y;
            Xs[xcc + 2][xr] = v.z; Xs[xcc + 3][xr] = v.w;
        } else {
            const float2 v = *(const float2*)Xp;
            Xs[xcc + 0][xr] = v.x; Xs[xcc + 1][xr] = v.y;
        }
        if constexpr (LB == 4) {
            *(float4*)&Bs[br][bc] = *(const float4*)Bp;
        } else {
            *(float2*)&Bs[br][bc] = *(const float2*)Bp;
        }
        __syncthreads();
#pragma unroll
        for (int kk = 0; kk < BK; ++kk) {
            float a[TM], b[TN];
#pragma unroll
            for (int i = 0; i < TM; ++i) a[i] = Xs[kk][ty * TM + i];
#pragma unroll
            for (int j = 0; j < TN; ++j) b[j] = Bs[kk][tx * TN + j];
#pragma unroll
            for (int i = 0; i < TM; ++i)
#pragma unroll
                for (int j = 0; j < TN; ++j) acc[i][j] = fmaf(a[i], b[j], acc[i][j]);
        }
        __syncthreads();
        Xp += BK;
        Bp += (long)BK * ldb;
    }

#pragma unroll
    for (int i = 0; i < TM; ++i) {
        const long m = m0 + (long)ty * TM + i;
        float bv = 0.f;
        if (BIAS) bv = bias[(int)((m / LL) & (CO - 1))];
        const long obase = m * (long)ldo + n0 + tx * TN;
        long cbase = 0;
        if constexpr (ADDC0) cbase = m * (long)ldc + n0 + tx * TN;
#pragma unroll
        for (int j = 0; j < TN; ++j) {
            float p = acc[i][j];
            if (RELU) p = fmaxf(p, 0.f);
            p *= alpha;
            float c = 0.f;
            if constexpr (ADDC0) c = C0[cbase + j];
            const float res = c + p + bv;
            Out[obase + j] = res;
            if constexpr (STB16) outb[obase + j] = f2bf(res);
        }
    }
}

// =====================================================================
__global__ __launch_bounds__(256)
void zero_k(float* __restrict__ p, int n) {
    for (int i = blockIdx.x * 256 + threadIdx.x; i < n; i += gridDim.x * 256) p[i] = 0.f;
}

// split-K Gram with mismatched flatten orders (faithful)
__global__ __launch_bounds__(256)
void asmat_split(const float* __restrict__ sxg, float* __restrict__ am_raw) {
    __shared__ float Us[128][65];
    __shared__ float Wsh[128][65];
    __shared__ int rA[128], rB[128];
    const int i0 = blockIdx.x * 128;
    const int tid = threadIdx.x;
    if (tid < 128) {
        const int i = i0 + tid;
        const int c = i / 192;
        const int rem = i - c * 192;
        const int n = rem / 12;
        const int l = rem - n * 12;
        rA[tid] = (n * 32 + c) * 12 + l;
        const int l2 = i >> 9;
        const int rem2 = i & 511;
        rB[tid] = ((rem2 >> 5) * 32 + (rem2 & 31)) * 12 + l2;
    }
    __syncthreads();
    for (int idx = tid; idx < 128 * 64; idx += 256) {
        const int r = idx >> 6, s = idx & 63;
        Us[r][s] = sxg[rA[r] * 64 + s];
        Wsh[r][s] = sxg[rB[r] * 64 + s];
    }
    __syncthreads();
    const int ts = (tid & 15) * 4;
    const int tt = (tid >> 4) * 4;
    float acc[4][4];
#pragma unroll
    for (int i2 = 0; i2 < 4; ++i2)
#pragma unroll
        for (int j = 0; j < 4; ++j) acc[i2][j] = 0.f;
    for (int k = 0; k < 128; ++k) {
        float a[4], bv[4];
#pragma unroll
        for (int i2 = 0; i2 < 4; ++i2) a[i2] = Us[k][ts + i2];
#pragma unroll
        for (int j = 0; j < 4; ++j) bv[j] = Wsh[k][tt + j];
#pragma unroll
        for (int i2 = 0; i2 < 4; ++i2)
#pragma unroll
            for (int j = 0; j < 4; ++j) acc[i2][j] = fmaf(a[i2], bv[j], acc[i2][j]);
    }
#pragma unroll
    for (int i2 = 0; i2 < 4; ++i2)
#pragma unroll
        for (int j = 0; j < 4; ++j)
            atomicAdd(&am_raw[(ts + i2) * 64 + tt + j], acc[i2][j]);
}

// sup[0] = softmax(rownorm(relu(raw-0.5))), sup[1] = same on transpose
__global__ __launch_bounds__(64)
void supbuild_k(const float* __restrict__ am_raw, float* __restrict__ sup) {
    __shared__ float a[64][65];
    for (int idx = threadIdx.x; idx < 4096; idx += 64) {
        const float v = am_raw[idx] - 0.5f;
        a[idx >> 6][idx & 63] = v > 0.f ? v : 0.f;
    }
    __syncthreads();
    const int r = threadIdx.x;
    {
        float rs = 0.f;
        for (int j = 0; j < 64; ++j) rs += a[r][j];
        const float dinv = rs > 0.f ? 1.f / rs : 0.f;
        float mx = -1e30f;
        for (int j = 0; j < 64; ++j) mx = fmaxf(mx, a[r][j] * dinv);
        float se = 0.f;
        for (int j = 0; j < 64; ++j) se += expf(a[r][j] * dinv - mx);
        const float inv = 1.f / se;
        for (int j = 0; j < 64; ++j) sup[r * 64 + j] = expf(a[r][j] * dinv - mx) * inv;
    }
    {
        float rs = 0.f;
        for (int j = 0; j < 64; ++j) rs += a[j][r];
        const float dinv = rs > 0.f ? 1.f / rs : 0.f;
        float mx = -1e30f;
        for (int j = 0; j < 64; ++j) mx = fmaxf(mx, a[j][r] * dinv);
        float se = 0.f;
        for (int j = 0; j < 64; ++j) se += expf(a[j][r] * dinv - mx);
        const float inv = 1.f / se;
        for (int j = 0; j < 64; ++j) sup[4096 + r * 64 + j] = expf(a[j][r] * dinv - mx) * inv;
    }
}

// =====================================================================
extern "C" void kernel_launch(void* const* d_in, const int* in_sizes, int n_in,
                              void* d_out, int out_size, void* d_ws, size_t ws_size,
                              hipStream_t stream) {
    (void)in_sizes; (void)n_in; (void)out_size; (void)ws_size;
    const float* x    = (const float*)d_in[0];
    const float* sup  = (const float*)d_in[1];  // [2, V, V]
    const float* supc = (const float*)d_in[2];  // [2, VC, VC]
    const float* acs  = (const float*)d_in[3];  // [VC, S]
    const float* afc  = (const float*)d_in[4];  // [V, VC]
    const float* W    = (const float*)d_in[5];  // [32, 96]
    const float* b    = (const float*)d_in[6];  // [32]
    float* ws = (float*)d_ws;

    // --- region A [0, 12,582,912): Btu bf16 (from step 5); xt eliminated
    unsigned short* Btu = (unsigned short*)ws;                // bf16 [2048][4096]
    float* yc0  = ws + 4456448;
    float* yc12 = ws + 6029312;
    float* ys0  = ws + 9175040;
    float* ys12 = ws + 9568256;
    float* hc   = ws + 10354688;
    float* hs   = ws + 11927552;
    float* am   = ws + 12320768;
    float* sups = ws + 12324864;
    float* acsT = ws + 12333056;                              // ends 12,349,440
    // --- fixed regions
    float* hf   = ws + 12582912;                              // y0 then hf
    float* xc   = ws + 25165824;
    float* sxg  = ws + 26738688;
    unsigned short* afcTb = (unsigned short*)(ws + 27131904); // bf16 [256][2048]
    unsigned short* afcb  = (unsigned short*)(ws + 27394048); // bf16 [2048][256]
    // ws total 27,656,192 floats (~110.6 MB)

    // --- d_out doubles as scratch (dead before final output writes)
    float* out_f = (float*)d_out;
    unsigned short* xtb  = (unsigned short*)d_out;            // bf16 [6144][2048], steps 1-3
    unsigned short* y12u = (unsigned short*)d_out;            // bf16 [6144][4096], steps 4-11
    unsigned short* hfb  = (unsigned short*)d_out;            // bf16 [6144][2048], steps 15-19
    unsigned short* hcb  = ((unsigned short*)d_out) + 12582912;  // bf16 [6144][256]
    float* hf_out = out_f;
    float* hc_out = out_f + 12582912;
    float* hs_out = out_f + 14155776;

    // 1. xtb = bf16 transpose(x) only (fp32 xt copy eliminated)
    transpose_vb<<<dim3(VV / 128, NB * CC), 256, 0, stream>>>(x, xtb);
    // 2. afcb + afcTb in one pass
    cvt_afc_both<<<dim3(VCC / 32, VV / 32), 256, 0, stream>>>(afc, afcb, afcTb);
    // 3. xc = xtb @ afc  (MFMA BN=64; B^T = afcTb)
    gemm_mfma<64, false, false, false, false, false><<<dim3(VCC / 64, MM / 128), 256, 0, stream>>>(
        xtb, VV, afcTb, VV, nullptr, 0, nullptr, xc, VCC, nullptr, VV, 1.0f);
    // 4. fused fine chanmix (reads x directly): y0 -> hf, y12 -> d_out
    //    (clobbers xtb -- dead after step 3)
    chanmix_fuse<<<dim3(VV / 64, NB), 256, 0, stream>>>(x, W, hf, y12u);
    // 5. Btu = bf16([A1;A2]^T) [2048][4096]
    cvt_T_bf16_k<<<dim3(VV / 32, 2 * VV / 32), 256, 0, stream>>>(sup, Btu, 2 * VV, VV);
    // 6. sxg = xc @ acs (fp32)
    gemm_k<64, 64, 16, 4, 4, false, false, false, false><<<dim3(1, MM / 64), 256, 0, stream>>>(
        xc, VCC, acs, SS, nullptr, 0, nullptr, sxg, SS, nullptr, VCC, 1.0f);
    // 7. coarse chanmix
    chanmix_k<<<dim3(12, 16), 256, 0, stream>>>(xc, W, LL * VCC, VCC, yc0, yc12, 2 * VCC);
    // 8. super chanmix
    chanmix_k<<<dim3(3, 16), 256, 0, stream>>>(sxg, W, LL * SS, SS, ys0, ys12, 2 * SS);
    // 9. gram + supports
    zero_k<<<dim3(4), 256, 0, stream>>>(am, 4096);
    asmat_split<<<dim3(48), 256, 0, stream>>>(sxg, am);
    supbuild_k<<<dim3(1), 64, 0, stream>>>(am, sups);
    // 10. K3 (192x256 8-wave counted-vmcnt MFMA): hf = y0 + y12 @ [A1;A2] + bias
    gemm_mfma256<<<dim3(VV / 256, MM / 192), 512, 0, stream>>>(
        y12u, 4096, Btu, 4096, hf, VV, b, hf, VV, 4096);
    // 11. hc = yc0 + yc12 @ [Ac1;Ac2] + bias (fp32)
    gemm_k<64, 64, 16, 4, 4, false, true, true, false><<<dim3(VCC / 64, MM / 64), 256, 0, stream>>>(
        yc12, 2 * VCC, supc, VCC, yc0, VCC, b, hc, VCC, nullptr, 2 * VCC, 1.0f);
    // 12. hs = ys0 + ys12 @ [As1;As2] + bias (fp32)
    gemm_k<64, 64, 16, 4, 4, false, true, true, false><<<dim3(1, MM / 64), 256, 0, stream>>>(
        ys12, 2 * SS, sups, SS, ys0, SS, b, hs, SS, nullptr, 2 * SS, 1.0f);
    // 13. acsT (fp32)
    transpose2d<<<dim3(SS / 32, VCC / 32), 256, 0, stream>>>(acs, acsT, VCC, SS);
    // 14. hc += 0.8 * relu(hs @ acs^T), dual-store hcb bf16 (y12u dead)
    gemm_k<64, 64, 16, 4, 4, true, true, false, true><<<dim3(VCC / 64, MM / 64), 256, 0, stream>>>(
        hs, SS, acsT, VCC, hc, VCC, nullptr, hc, VCC, hcb, SS, 0.8f);
    // 15. hf += 0.2 * relu(hcb @ afc^T) (MFMA, swizzle), dual-store hfb bf16
    gemm_mfma<128, true, true, true, false, true><<<dim3(VV / 128, MM / 128), 256, 0, stream>>>(
        hcb, VCC, afcb, VCC, hf, VV, nullptr, hf, VV, hfb, VCC, 0.2f);
    // 16. hc += 0.2 * relu(hfb @ afc) (MFMA BN=64; B^T = afcTb)
    gemm_mfma<64, false, true, true, false, false><<<dim3(VCC / 64, MM / 128), 256, 0, stream>>>(
        hfb, VV, afcTb, VV, hc, VCC, nullptr, hc, VCC, nullptr, VV, 0.2f);
    // 17. hs += 0.2 * relu(hc @ acs) (fp32, K=256)
    gemm_k<64, 64, 16, 4, 4, true, true, false, false><<<dim3(1, MM / 64), 256, 0, stream>>>(
        hc, VCC, acs, SS, hs, SS, nullptr, hs, SS, nullptr, VCC, 0.2f);
    // 18. node-last -> reference layout [*, node, L]
    transpose_lv<<<dim3(VV / 128, NB * CO), 256, 0, stream>>>(hf, hf_out, VV, 128);
    transpose_lv<<<dim3(VCC / 128, NB * CO), 256, 0, stream>>>(hc, hc_out, VCC, 128);
    transpose_lv<<<dim3(1, NB * CO), 256, 0, stream>>>(hs, hs_out, SS, 64);
}

// Round 8
// 591.246 us; speedup vs baseline: 1.1121x; 1.1121x over previous
//
#include <hip/hip_runtime.h>

// ---------------- problem dims ----------------
constexpr int NB = 16;    // batch
constexpr int CC = 32;    // in channels
constexpr int VV = 2048;  // fine nodes
constexpr int VCC = 256;  // coarse nodes
constexpr int SS = 64;    // super nodes
constexpr int LL = 12;    // time
constexpr int CO = 32;    // out channels
constexpr long MM = (long)NB * CO * LL;  // 6144 rows in node-last layout

typedef __attribute__((ext_vector_type(8))) __bf16 bf16x8;
typedef __attribute__((ext_vector_type(4))) float f32x4;

__device__ __forceinline__ unsigned short f2bf(float f) {
    unsigned u = __float_as_uint(f);
    unsigned r = u + 0x7FFFu + ((u >> 16) & 1u);  // RNE
    return (unsigned short)(r >> 16);
}

__device__ __forceinline__ void gl_lds16(const void* g, void* l) {
    __builtin_amdgcn_global_load_lds(
        (const __attribute__((address_space(1))) void*)g,
        (__attribute__((address_space(3))) void*)l, 16, 0, 0);
}

// =====================================================================
// K1: x [nc, V, 12] -> xt fp32 [nc, 12, V] AND xtb bf16 (same layout)
// (round-7's fused variant regressed 140us: 116KiB LDS -> 1 blk/CU,
//  10.8% occupancy. Split form restored.)
__global__ __launch_bounds__(256)
void transpose_vl(const float* __restrict__ in, float* __restrict__ out,
                  unsigned short* __restrict__ outb) {
    __shared__ float t[128 * 13];
    const long nc = blockIdx.y;
    const int v0 = blockIdx.x * 128;
    const float* src = in + (nc * VV + v0) * 12;
    for (int f = threadIdx.x; f < 128 * 12; f += 256) {
        const int vv = f / 12, l = f - vv * 12;
        t[vv * 13 + l] = src[f];
    }
    __syncthreads();
    float* dst = out + nc * 12L * VV;
    unsigned short* dstb = outb + nc * 12L * VV;
    for (int g = threadIdx.x; g < 128 * 12; g += 256) {
        int l = g >> 7, vv = g & 127;
        const float v = t[vv * 13 + l];
        dst[(long)l * VV + v0 + vv] = v;
        dstb[(long)l * VV + v0 + vv] = f2bf(v);
    }
}

// out-transpose: in [nc, 12, Kn] -> out [nc, Kn, 12]  (13-pad)
__global__ __launch_bounds__(256)
void transpose_lv(const float* __restrict__ in, float* __restrict__ out, int Kn, int TW) {
    __shared__ float t[128 * 13];
    const long nc = blockIdx.y;
    const int v0 = blockIdx.x * TW;
    const float* src = in + nc * 12L * Kn;
    for (int g = threadIdx.x; g < TW * 12; g += 256) {
        int l = g / TW, vv = g - l * TW;
        t[vv * 13 + l] = src[(long)l * Kn + v0 + vv];
    }
    __syncthreads();
    float* dst = out + (nc * Kn + v0) * 12L;
    for (int f = threadIdx.x; f < TW * 12; f += 256) {
        const int vv = f / 12, l = f - vv * 12;
        dst[f] = t[vv * 13 + l];
    }
}

// small dense fp32 transpose: in [rows, cols] -> out [cols, rows]
__global__ __launch_bounds__(256)
void transpose2d(const float* __restrict__ in, float* __restrict__ out, int rows, int cols) {
    __shared__ float t[32][33];
    const int r0 = blockIdx.y * 32, c0 = blockIdx.x * 32;
    const int ty = threadIdx.x / 32, tx = threadIdx.x % 32;
    for (int i = ty; i < 32; i += 8) t[i][tx] = in[(long)(r0 + i) * cols + c0 + tx];
    __syncthreads();
    for (int i = ty; i < 32; i += 8) out[(long)(c0 + i) * rows + r0 + tx] = t[tx][i];
}

// fp32 [R,C] -> bf16 transpose [C,R]
__global__ __launch_bounds__(256)
void cvt_T_bf16_k(const float* __restrict__ in, unsigned short* __restrict__ out,
                  int R, int Ccols) {
    __shared__ float t[32][33];
    const int r0 = blockIdx.y * 32, c0 = blockIdx.x * 32;
    const int ty = threadIdx.x / 32, tx = threadIdx.x % 32;
    for (int i = ty; i < 32; i += 8) t[i][tx] = in[(long)(r0 + i) * Ccols + c0 + tx];
    __syncthreads();
    for (int i = ty; i < 32; i += 8) out[(long)(c0 + i) * R + r0 + tx] = f2bf(t[tx][i]);
}

// afc [2048,256] fp32 -> afcb bf16 [2048,256] AND afcTb bf16 [256,2048]
__global__ __launch_bounds__(256)
void cvt_afc_both(const float* __restrict__ in, unsigned short* __restrict__ outn,
                  unsigned short* __restrict__ outt) {
    __shared__ float t[32][33];
    const int r0 = blockIdx.y * 32, c0 = blockIdx.x * 32;
    const int ty = threadIdx.x / 32, tx = threadIdx.x % 32;
    for (int i = ty; i < 32; i += 8) {
        const float v = in[(long)(r0 + i) * VCC + c0 + tx];
        t[i][tx] = v;
        outn[(long)(r0 + i) * VCC + c0 + tx] = f2bf(v);
    }
    __syncthreads();
    for (int i = ty; i < 32; i += 8)
        outt[(long)(c0 + i) * VV + r0 + tx] = f2bf(t[tx][i]);
}

// =====================================================================
// fine channel mix: xt [16,32,24576] -> y0 fp32 [M,2048], y12 bf16 [M,4096]
__global__ __launch_bounds__(256)
void chanmix_fine(const float* __restrict__ in, const float* __restrict__ Wt,
                  float* __restrict__ y0, unsigned short* __restrict__ y12) {
    __shared__ float Ws[CO * 96];
    for (int idx = threadIdx.x; idx < CO * 96; idx += 256) Ws[idx] = Wt[idx];
    __syncthreads();
    const int nb = blockIdx.y;
    const int r = blockIdx.x * 256 + threadIdx.x;
    const int R = LL * VV;
    const int l = r / VV, k = r - l * VV;
    float xv[CC];
#pragma unroll
    for (int c = 0; c < CC; ++c) xv[c] = in[((long)(nb * CC + c)) * R + r];
    for (int o = 0; o < CO; ++o) {
        float a0 = 0.f, a1 = 0.f, a2 = 0.f;
#pragma unroll
        for (int c = 0; c < CC; ++c) {
            const float x = xv[c];
            a0 = fmaf(Ws[o * 96 + c], x, a0);
            a1 = fmaf(Ws[o * 96 + 32 + c], x, a1);
            a2 = fmaf(Ws[o * 96 + 64 + c], x, a2);
        }
        const long mrow = (long)(nb * CO + o) * LL + l;
        y0[mrow * VV + k] = a0;
        y12[mrow * 4096 + k] = f2bf(a1);
        y12[mrow * 4096 + 2048 + k] = f2bf(a2);
    }
}

// coarse/super channel mix (fp32 outputs)
__global__ __launch_bounds__(256)
void chanmix_k(const float* __restrict__ in, const float* __restrict__ Wt,
               int R, int Kn, float* __restrict__ o0,
               float* __restrict__ o1, int ld1) {
    __shared__ float Ws[CO * 96];
    for (int idx = threadIdx.x; idx < CO * 96; idx += 256) Ws[idx] = Wt[idx];
    __syncthreads();
    const int nb = blockIdx.y;
    const int r = blockIdx.x * 256 + threadIdx.x;
    if (r >= R) return;
    const int l = r / Kn, k = r - l * Kn;
    float xv[CC];
#pragma unroll
    for (int c = 0; c < CC; ++c) xv[c] = in[((long)(nb * CC + c)) * R + r];
    for (int o = 0; o < CO; ++o) {
        float a0 = 0.f, a1 = 0.f, a2 = 0.f;
#pragma unroll
        for (int c = 0; c < CC; ++c) {
            const float x = xv[c];
            a0 = fmaf(Ws[o * 96 + c], x, a0);
            a1 = fmaf(Ws[o * 96 + 32 + c], x, a1);
            a2 = fmaf(Ws[o * 96 + 64 + c], x, a2);
        }
        const long mrow = (long)(nb * CO + o) * LL + l;
        o0[mrow * Kn + k] = a0;
        o1[mrow * ld1 + k] = a1;
        o1[mrow * ld1 + Kn + k] = a2;
    }
}

// =====================================================================
// bf16 MFMA GEMM: Out[m,n] = (ADDC0? C0[m,n]:0) + (BIAS? bias[(m/12)&31]:0)
//                           + alpha * (RELU? relu(A@B) : A@B)
// A [M,K] bf16 (lda), Bt [N,K] bf16 (ldb) (= B^T). Tile 128xBN, BK=64,
// 4 waves, 16x16x32 MFMA, XOR-swizzled LDS, global_load_lds width-16.
template <int BN, bool SWIZ, bool RELU, bool ADDC0, bool BIAS, bool STB16>
__global__ __launch_bounds__(256)
void gemm_mfma(const unsigned short* __restrict__ A, int lda,
               const unsigned short* __restrict__ Bt, int ldb,
               const float* __restrict__ C0, int ldc,
               const float* __restrict__ bias,
               float* __restrict__ Out, int ldo,
               unsigned short* __restrict__ OutB, int K, float alpha) {
    constexpr int TNT = BN / 32;   // 16-tiles per wave along n (4 or 2)
    constexpr int QB = BN / 32;    // B staging iters (4 or 2)
    constexpr int WN = BN / 2;     // wave n-extent
    __shared__ __align__(16) unsigned short As[128 * 64];
    __shared__ __align__(16) unsigned short Bs[BN * 64];
    const int tid = threadIdx.x;
    const int lane = tid & 63;
    const int w = tid >> 6;

    int pid_m, pid_n;
    if constexpr (SWIZ) {
        const int id = blockIdx.y * gridDim.x + blockIdx.x;
        const int npg = 8 * gridDim.x;
        const int rem = id % npg;
        pid_m = (id / npg) * 8 + (rem & 7);
        pid_n = rem >> 3;
    } else {
        pid_m = blockIdx.y;
        pid_n = blockIdx.x;
    }
    const long m0 = (long)pid_m * 128;
    const int n0 = pid_n * BN;

    long offA[4], offB[QB];
#pragma unroll
    for (int q = 0; q < 4; ++q) {
        const int t = q * 256 + tid;
        const int row = t >> 3, pos = t & 7;
        const int lc = pos ^ (row & 7);
        offA[q] = (m0 + row) * (long)lda + lc * 8;
    }
#pragma unroll
    for (int q = 0; q < QB; ++q) {
        const int t = q * 256 + tid;
        const int row = t >> 3, pos = t & 7;
        const int lc = pos ^ (row & 7);
        offB[q] = (long)(n0 + row) * ldb + lc * 8;
    }
    const int wm = (w & 1) * 64, wn = (w >> 1) * WN;
    const int mrow = lane & 15;
    const int quad = lane >> 4;

    f32x4 acc[4][TNT];
#pragma unroll
    for (int i = 0; i < 4; ++i)
#pragma unroll
        for (int j = 0; j < TNT; ++j) acc[i][j] = (f32x4){0.f, 0.f, 0.f, 0.f};

    for (int k0 = 0; k0 < K; k0 += 64) {
#pragma unroll
        for (int q = 0; q < 4; ++q)
            gl_lds16(A + offA[q] + k0, &As[(q * 256 + w * 64) * 8]);
#pragma unroll
        for (int q = 0; q < QB; ++q)
            gl_lds16(Bt + offB[q] + k0, &Bs[(q * 256 + w * 64) * 8]);
        __syncthreads();
#pragma unroll
        for (int ks = 0; ks < 2; ++ks) {
            bf16x8 af[4], bfr[TNT];
            const int pos = (ks * 4 + quad) ^ (mrow & 7);
#pragma unroll
            for (int tm = 0; tm < 4; ++tm) {
                const int r = wm + tm * 16 + mrow;
                af[tm] = *(const bf16x8*)&As[r * 64 + pos * 8];
            }
#pragma unroll
            for (int tn = 0; tn < TNT; ++tn) {
                const int r = wn + tn * 16 + mrow;
                bfr[tn] = *(const bf16x8*)&Bs[r * 64 + pos * 8];
            }
#pragma unroll
            for (int tm = 0; tm < 4; ++tm)
#pragma unroll
                for (int tn = 0; tn < TNT; ++tn)
                    acc[tm][tn] = __builtin_amdgcn_mfma_f32_16x16x32_bf16(
                        af[tm], bfr[tn], acc[tm][tn], 0, 0, 0);
        }
        __syncthreads();
    }

    // C/D layout: col = lane&15, row = quad*4 + reg
#pragma unroll
    for (int tm = 0; tm < 4; ++tm) {
#pragma unroll
        for (int tn = 0; tn < TNT; ++tn) {
            const int n = n0 + wn + tn * 16 + mrow;
#pragma unroll
            for (int reg = 0; reg < 4; ++reg) {
                const long m = m0 + wm + tm * 16 + quad * 4 + reg;
                float p = acc[tm][tn][reg];
                if (RELU) p = fmaxf(p, 0.f);
                p *= alpha;
                float c = 0.f;
                if constexpr (ADDC0) c = C0[m * (long)ldc + n];
                if (BIAS) c += bias[(int)((m / LL) & (CO - 1))];
                const float res = c + p;
                Out[m * (long)ldo + n] = res;
                if constexpr (STB16) OutB[m * (long)ldo + n] = f2bf(res);
            }
        }
    }
}

// =====================================================================
// 192x256-tile, 8-wave, counted-vmcnt bf16 MFMA GEMM (VERIFIED round-3
// schedule: 108 us, MfmaUtil 40%). Round-5's 4-phase fine-gated variant
// REGRESSED (142 us, m141/m196 order-pinning) -- keep this structure.
// Grid (8,32) = 256 blocks = exact 1-block/CU fill.
__global__ __launch_bounds__(512)
void gemm_mfma256(const unsigned short* __restrict__ A, int lda,
                  const unsigned short* __restrict__ Bt, int ldb,
                  const float* __restrict__ C0, int ldc,
                  const float* __restrict__ bias,
                  float* __restrict__ Out, int ldo, int K) {
    __shared__ __align__(16) unsigned short As[2][192 * 64];
    __shared__ __align__(16) unsigned short Bs[2][256 * 64];
    const int tid = threadIdx.x;
    const int lane = tid & 63;
    const int w = tid >> 6;          // wave 0..7
    const int wr = w >> 2;           // 0..1 : M half (rows wr*96..+95)
    const int wc = w & 3;            // 0..3 : N quarter (cols wc*64..+63)
    const int mrow = lane & 15;
    const int quad = lane >> 4;

    const long m0 = (long)blockIdx.y * 192;
    const int n0 = blockIdx.x * 256;

    long offA[3], offB[4];
#pragma unroll
    for (int q = 0; q < 3; ++q) {
        const int t = q * 512 + tid;
        const int row = t >> 3, pos = t & 7;
        const int lc = pos ^ (row & 7);
        offA[q] = (m0 + row) * (long)lda + lc * 8;
    }
#pragma unroll
    for (int q = 0; q < 4; ++q) {
        const int t = q * 512 + tid;
        const int row = t >> 3, pos = t & 7;
        const int lc = pos ^ (row & 7);
        offB[q] = (long)(n0 + row) * ldb + lc * 8;
    }
    const int NT = K >> 6;

#define STAGE_A(b_, t_)                                                      \
    do {                                                                     \
        gl_lds16(A + offA[0] + (long)(t_) * 64, &As[b_][w * 512]);           \
        gl_lds16(A + offA[1] + (long)(t_) * 64, &As[b_][4096 + w * 512]);    \
        gl_lds16(A + offA[2] + (long)(t_) * 64, &As[b_][8192 + w * 512]);    \
    } while (0)
#define STAGE_B_LO(b_, t_)                                                   \
    do {                                                                     \
        gl_lds16(Bt + offB[0] + (long)(t_) * 64, &Bs[b_][w * 512]);          \
        gl_lds16(Bt + offB[1] + (long)(t_) * 64, &Bs[b_][4096 + w * 512]);   \
    } while (0)
#define STAGE_B_HI(b_, t_)                                                   \
    do {                                                                     \
        gl_lds16(Bt + offB[2] + (long)(t_) * 64, &Bs[b_][8192 + w * 512]);   \
        gl_lds16(Bt + offB[3] + (long)(t_) * 64, &Bs[b_][12288 + w * 512]);  \
    } while (0)

    const int p0 = (quad ^ (mrow & 7)) * 8;           // ks0 chunk
    const int p1 = ((4 + quad) ^ (mrow & 7)) * 8;     // ks1 chunk
    const int ra = (wr * 96 + mrow) * 64;             // + tm*1024
    const int rb = (wc * 64 + mrow) * 64;             // + tn*1024

    f32x4 acc[6][4];
#pragma unroll
    for (int i = 0; i < 6; ++i)
#pragma unroll
        for (int j = 0; j < 4; ++j) acc[i][j] = (f32x4){0.f, 0.f, 0.f, 0.f};

    // prologue: tile0 fully (7 wave-loads), tile1 A + B-lo (5 wave-loads)
    STAGE_A(0, 0); STAGE_B_LO(0, 0); STAGE_B_HI(0, 0);
    if (NT > 1) {
        STAGE_A(1, 1); STAGE_B_LO(1, 1);
        asm volatile("s_waitcnt vmcnt(5)" ::: "memory");  // tile0 landed
    } else {
        asm volatile("s_waitcnt vmcnt(0)" ::: "memory");
    }
    __builtin_amdgcn_sched_barrier(0);
    __builtin_amdgcn_s_barrier();
    __builtin_amdgcn_sched_barrier(0);

    for (int t = 0; t < NT; ++t) {
        const int buf = t & 1;
        bf16x8 a0[6], b0[4], a1[6], b1[4];
#pragma unroll
        for (int tm = 0; tm < 6; ++tm)
            a0[tm] = *(const bf16x8*)&As[buf][ra + tm * 1024 + p0];
#pragma unroll
        for (int tn = 0; tn < 4; ++tn)
            b0[tn] = *(const bf16x8*)&Bs[buf][rb + tn * 1024 + p0];
        if (t + 1 < NT) { STAGE_B_HI(buf ^ 1, t + 1); }  // other buffer: safe
        __builtin_amdgcn_s_setprio(1);
#pragma unroll
        for (int tm = 0; tm < 6; ++tm)
#pragma unroll
            for (int tn = 0; tn < 4; ++tn)
                acc[tm][tn] = __builtin_amdgcn_mfma_f32_16x16x32_bf16(
                    a0[tm], b0[tn], acc[tm][tn], 0, 0, 0);
        __builtin_amdgcn_s_setprio(0);
#pragma unroll
        for (int tm = 0; tm < 6; ++tm)
            a1[tm] = *(const bf16x8*)&As[buf][ra + tm * 1024 + p1];
#pragma unroll
        for (int tn = 0; tn < 4; ++tn)
            b1[tn] = *(const bf16x8*)&Bs[buf][rb + tn * 1024 + p1];
        asm volatile("s_waitcnt lgkmcnt(0)" ::: "memory");  // drain buf reads
        __builtin_amdgcn_sched_barrier(0);
        __builtin_amdgcn_s_barrier();
        __builtin_amdgcn_sched_barrier(0);
        // all waves' reads of buf done -> safe to overwrite with tile t+2
        if (t + 2 < NT) { STAGE_A(buf, t + 2); STAGE_B_LO(buf, t + 2); }
        __builtin_amdgcn_s_setprio(1);
#pragma unroll
        for (int tm = 0; tm < 6; ++tm)
#pragma unroll
            for (int tn = 0; tn < 4; ++tn)
                acc[tm][tn] = __builtin_amdgcn_mfma_f32_16x16x32_bf16(
                    a1[tm], b1[tn], acc[tm][tn], 0, 0, 0);
        __builtin_amdgcn_s_setprio(0);
        if (t + 2 < NT) {
            asm volatile("s_waitcnt vmcnt(5)" ::: "memory");  // tile t+1 landed
        } else if (t + 1 < NT) {
            asm volatile("s_waitcnt vmcnt(0)" ::: "memory");  // tail drain
        }
        __builtin_amdgcn_sched_barrier(0);
        __builtin_amdgcn_s_barrier();
        __builtin_amdgcn_sched_barrier(0);
    }
#undef STAGE_A
#undef STAGE_B_LO
#undef STAGE_B_HI

    // epilogue: C/D layout col = lane&15, row = quad*4 + reg
#pragma unroll
    for (int tm = 0; tm < 6; ++tm) {
#pragma unroll
        for (int tn = 0; tn < 4; ++tn) {
            const int n = n0 + wc * 64 + tn * 16 + mrow;
#pragma unroll
            for (int reg = 0; reg < 4; ++reg) {
                const long m = m0 + wr * 96 + tm * 16 + quad * 4 + reg;
                float p = acc[tm][tn][reg];
                float c = C0[m * (long)ldc + n];
                c += bias[(int)((m / LL) & (CO - 1))];
                Out[m * (long)ldo + n] = c + p;
            }
        }
    }
}

// =====================================================================
// generic fp32 GEMM (narrow / accuracy-critical ops); optional bf16 dual store
// BM=32,TM=2 instantiation used for N=64 ops (2x grid coverage vs BM=64;
// per-element FMA chain is kk-ascending regardless of BM -> bit-exact).
template <int BM, int BN, int BK, int TM, int TN, bool RELU, bool ADDC0, bool BIAS, bool STB16>
__global__ __launch_bounds__(256)
void gemm_k(const float* __restrict__ X, int ldx,
            const float* __restrict__ Bm, int ldb,
            const float* __restrict__ C0, int ldc,
            const float* __restrict__ bias,
            float* __restrict__ Out, int ldo,
            unsigned short* __restrict__ outb, int K, float alpha) {
    constexpr int TX = BN / TN;
    constexpr int LX = (BM * BK) / 256;
    constexpr int LB = (BN * BK) / 256;
    __shared__ float Xs[BK][BM + 4];
    __shared__ float Bs[BK][BN + 4];
    const int tid = threadIdx.x;
    const int tx = tid % TX, ty = tid / TX;
    const long m0 = (long)blockIdx.y * BM;
    const int n0 = blockIdx.x * BN;
    const int xr = tid / (BK / LX);
    const int xcc = (tid % (BK / LX)) * LX;
    const int br = tid / (BN / LB);
    const int bc = (tid % (BN / LB)) * LB;

    float acc[TM][TN];
#pragma unroll
    for (int i = 0; i < TM; ++i)
#pragma unroll
        for (int j = 0; j < TN; ++j) acc[i][j] = 0.f;

    const float* Xp = X + (m0 + xr) * (long)ldx + xcc;
    const float* Bp = Bm + (long)br * ldb + n0 + bc;

    for (int k0 = 0; k0 < K; k0 += BK) {
        if constexpr (LX == 4) {
            const float4 v = *(const float4*)Xp;
            Xs[xcc + 0][xr] = v.x; Xs[xcc + 1][xr] = v.y;
            Xs[xcc + 2][xr] = v.z; Xs[xcc + 3][xr] = v.w;
        } else {
            const float2 v = *(const float2*)Xp;
            Xs[xcc + 0][xr] = v.x; Xs[xcc + 1][xr] = v.y;
        }
        if constexpr (LB == 4) {
            *(float4*)&Bs[br][bc] = *(const float4*)Bp;
        } else {
            *(float2*)&Bs[br][bc] = *(const float2*)Bp;
        }
        __syncthreads();
#pragma unroll
        for (int kk = 0; kk < BK; ++kk) {
            float a[TM], b[TN];
#pragma unroll
            for (int i = 0; i < TM; ++i) a[i] = Xs[kk][ty * TM + i];
#pragma unroll
            for (int j = 0; j < TN; ++j) b[j] = Bs[kk][tx * TN + j];
#pragma unroll
            for (int i = 0; i < TM; ++i)
#pragma unroll
                for (int j = 0; j < TN; ++j) acc[i][j] = fmaf(a[i], b[j], acc[i][j]);
        }
        __syncthreads();
        Xp += BK;
        Bp += (long)BK * ldb;
    }

#pragma unroll
    for (int i = 0; i < TM; ++i) {
        const long m = m0 + (long)ty * TM + i;
        float bv = 0.f;
        if (BIAS) bv = bias[(int)((m / LL) & (CO - 1))];
        const long obase = m * (long)ldo + n0 + tx * TN;
        long cbase = 0;
        if constexpr (ADDC0) cbase = m * (long)ldc + n0 + tx * TN;
#pragma unroll
        for (int j = 0; j < TN; ++j) {
            float p = acc[i][j];
            if (RELU) p = fmaxf(p, 0.f);
            p *= alpha;
            float c = 0.f;
            if constexpr (ADDC0) c = C0[cbase + j];
            const float res = c + p + bv;
            Out[obase + j] = res;
            if constexpr (STB16) outb[obase + j] = f2bf(res);
        }
    }
}

// =====================================================================
__global__ __launch_bounds__(256)
void zero_k(float* __restrict__ p, int n) {
    for (int i = blockIdx.x * 256 + threadIdx.x; i < n; i += gridDim.x * 256) p[i] = 0.f;
}

// split-K Gram with mismatched flatten orders (faithful)
__global__ __launch_bounds__(256)
void asmat_split(const float* __restrict__ sxg, float* __restrict__ am_raw) {
    __shared__ float Us[128][65];
    __shared__ float Wsh[128][65];
    __shared__ int rA[128], rB[128];
    const int i0 = blockIdx.x * 128;
    const int tid = threadIdx.x;
    if (tid < 128) {
        const int i = i0 + tid;
        const int c = i / 192;
        const int rem = i - c * 192;
        const int n = rem / 12;
        const int l = rem - n * 12;
        rA[tid] = (n * 32 + c) * 12 + l;
        const int l2 = i >> 9;
        const int rem2 = i & 511;
        rB[tid] = ((rem2 >> 5) * 32 + (rem2 & 31)) * 12 + l2;
    }
    __syncthreads();
    for (int idx = tid; idx < 128 * 64; idx += 256) {
        const int r = idx >> 6, s = idx & 63;
        Us[r][s] = sxg[rA[r] * 64 + s];
        Wsh[r][s] = sxg[rB[r] * 64 + s];
    }
    __syncthreads();
    const int ts = (tid & 15) * 4;
    const int tt = (tid >> 4) * 4;
    float acc[4][4];
#pragma unroll
    for (int i2 = 0; i2 < 4; ++i2)
#pragma unroll
        for (int j = 0; j < 4; ++j) acc[i2][j] = 0.f;
    for (int k = 0; k < 128; ++k) {
        float a[4], bv[4];
#pragma unroll
        for (int i2 = 0; i2 < 4; ++i2) a[i2] = Us[k][ts + i2];
#pragma unroll
        for (int j = 0; j < 4; ++j) bv[j] = Wsh[k][tt + j];
#pragma unroll
        for (int i2 = 0; i2 < 4; ++i2)
#pragma unroll
            for (int j = 0; j < 4; ++j) acc[i2][j] = fmaf(a[i2], bv[j], acc[i2][j]);
    }
#pragma unroll
    for (int i2 = 0; i2 < 4; ++i2)
#pragma unroll
        for (int j = 0; j < 4; ++j)
            atomicAdd(&am_raw[(ts + i2) * 64 + tt + j], acc[i2][j]);
}

// sup[0] = softmax(rownorm(relu(raw-0.5))), sup[1] = same on transpose
__global__ __launch_bounds__(64)
void supbuild_k(const float* __restrict__ am_raw, float* __restrict__ sup) {
    __shared__ float a[64][65];
    for (int idx = threadIdx.x; idx < 4096; idx += 64) {
        const float v = am_raw[idx] - 0.5f;
        a[idx >> 6][idx & 63] = v > 0.f ? v : 0.f;
    }
    __syncthreads();
    const int r = threadIdx.x;
    {
        float rs = 0.f;
        for (int j = 0; j < 64; ++j) rs += a[r][j];
        const float dinv = rs > 0.f ? 1.f / rs : 0.f;
        float mx = -1e30f;
        for (int j = 0; j < 64; ++j) mx = fmaxf(mx, a[r][j] * dinv);
        float se = 0.f;
        for (int j = 0; j < 64; ++j) se += expf(a[r][j] * dinv - mx);
        const float inv = 1.f / se;
        for (int j = 0; j < 64; ++j) sup[r * 64 + j] = expf(a[r][j] * dinv - mx) * inv;
    }
    {
        float rs = 0.f;
        for (int j = 0; j < 64; ++j) rs += a[j][r];
        const float dinv = rs > 0.f ? 1.f / rs : 0.f;
        float mx = -1e30f;
        for (int j = 0; j < 64; ++j) mx = fmaxf(mx, a[j][r] * dinv);
        float se = 0.f;
        for (int j = 0; j < 64; ++j) se += expf(a[j][r] * dinv - mx);
        const float inv = 1.f / se;
        for (int j = 0; j < 64; ++j) sup[4096 + r * 64 + j] = expf(a[j][r] * dinv - mx) * inv;
    }
}

// =====================================================================
extern "C" void kernel_launch(void* const* d_in, const int* in_sizes, int n_in,
                              void* d_out, int out_size, void* d_ws, size_t ws_size,
                              hipStream_t stream) {
    (void)in_sizes; (void)n_in; (void)out_size; (void)ws_size;
    const float* x    = (const float*)d_in[0];
    const float* sup  = (const float*)d_in[1];  // [2, V, V]
    const float* supc = (const float*)d_in[2];  // [2, VC, VC]
    const float* acs  = (const float*)d_in[3];  // [VC, S]
    const float* afc  = (const float*)d_in[4];  // [V, VC]
    const float* W    = (const float*)d_in[5];  // [32, 96]
    const float* b    = (const float*)d_in[6];  // [32]
    float* ws = (float*)d_ws;

    // --- region A [0, 12,582,912): xt fp32 (alive steps 1-4); then reused:
    float* xt = ws;
    unsigned short* Btu = (unsigned short*)ws;                // bf16 [2048][4096], from step 5
    float* yc0  = ws + 4456448;
    float* yc12 = ws + 6029312;
    float* ys0  = ws + 9175040;
    float* ys12 = ws + 9568256;
    float* hc   = ws + 10354688;
    float* hs   = ws + 11927552;
    float* am   = ws + 12320768;
    float* sups = ws + 12324864;
    float* acsT = ws + 12333056;                              // ends 12,349,440
    // --- fixed regions
    float* hf   = ws + 12582912;                              // y0 then hf
    float* xc   = ws + 25165824;
    float* sxg  = ws + 26738688;
    unsigned short* afcTb = (unsigned short*)(ws + 27131904); // bf16 [256][2048]
    unsigned short* afcb  = (unsigned short*)(ws + 27394048); // bf16 [2048][256]
    // ws total 27,656,192 floats (~110.6 MB)

    // --- d_out doubles as scratch (dead before final output writes)
    float* out_f = (float*)d_out;
    unsigned short* xtb  = (unsigned short*)d_out;            // bf16 [6144][2048], steps 1-3
    unsigned short* y12u = (unsigned short*)d_out;            // bf16 [6144][4096], steps 4-11
    unsigned short* hfb  = (unsigned short*)d_out;            // bf16 [6144][2048], steps 15-19
    unsigned short* hcb  = ((unsigned short*)d_out) + 12582912;  // bf16 [6144][256]
    float* hf_out = out_f;
    float* hc_out = out_f + 12582912;
    float* hs_out = out_f + 14155776;

    // 1. xt = transpose(x) (+ bf16 copy xtb into d_out)
    transpose_vl<<<dim3(VV / 128, NB * CC), 256, 0, stream>>>(x, xt, xtb);
    // 2. afcb + afcTb in one pass
    cvt_afc_both<<<dim3(VCC / 32, VV / 32), 256, 0, stream>>>(afc, afcb, afcTb);
    // 3. xc = xtb @ afc  (MFMA BN=64; B^T = afcTb)
    gemm_mfma<64, false, false, false, false, false><<<dim3(VCC / 64, MM / 128), 256, 0, stream>>>(
        xtb, VV, afcTb, VV, nullptr, 0, nullptr, xc, VCC, nullptr, VV, 1.0f);
    // 4. fine chanmix: y0 -> hf (fp32), y12 -> d_out (bf16; clobbers xtb - dead)
    chanmix_fine<<<dim3(96, 16), 256, 0, stream>>>(xt, W, hf, y12u);
    // 5. Btu = bf16([A1;A2]^T) [2048][4096]  (region A; xt dead after step 4)
    cvt_T_bf16_k<<<dim3(VV / 32, 2 * VV / 32), 256, 0, stream>>>(sup, Btu, 2 * VV, VV);
    // 6. sxg = xc @ acs (fp32, BM=32: grid (1,192) = 2x CU coverage vs 96)
    gemm_k<32, 64, 16, 2, 4, false, false, false, false><<<dim3(1, MM / 32), 256, 0, stream>>>(
        xc, VCC, acs, SS, nullptr, 0, nullptr, sxg, SS, nullptr, VCC, 1.0f);
    // 7. coarse chanmix
    chanmix_k<<<dim3(12, 16), 256, 0, stream>>>(xc, W, LL * VCC, VCC, yc0, yc12, 2 * VCC);
    // 8. super chanmix
    chanmix_k<<<dim3(3, 16), 256, 0, stream>>>(sxg, W, LL * SS, SS, ys0, ys12, 2 * SS);
    // 9. gram + supports
    zero_k<<<dim3(4), 256, 0, stream>>>(am, 4096);
    asmat_split<<<dim3(48), 256, 0, stream>>>(sxg, am);
    supbuild_k<<<dim3(1), 64, 0, stream>>>(am, sups);
    // 10. K3 (192x256 8-wave counted-vmcnt MFMA, round-3 schedule):
    //     hf = y0 + y12 @ [A1;A2] + bias. grid (8,32)=256 blocks.
    gemm_mfma256<<<dim3(VV / 256, MM / 192), 512, 0, stream>>>(
        y12u, 4096, Btu, 4096, hf, VV, b, hf, VV, 4096);
    // 11. hc = yc0 + yc12 @ [Ac1;Ac2] + bias (fp32, N=256: grid 384 ok)
    gemm_k<64, 64, 16, 4, 4, false, true, true, false><<<dim3(VCC / 64, MM / 64), 256, 0, stream>>>(
        yc12, 2 * VCC, supc, VCC, yc0, VCC, b, hc, VCC, nullptr, 2 * VCC, 1.0f);
    // 12. hs = ys0 + ys12 @ [As1;As2] + bias (fp32, BM=32: grid (1,192))
    gemm_k<32, 64, 16, 2, 4, false, true, true, false><<<dim3(1, MM / 32), 256, 0, stream>>>(
        ys12, 2 * SS, sups, SS, ys0, SS, b, hs, SS, nullptr, 2 * SS, 1.0f);
    // 13. acsT (fp32)
    transpose2d<<<dim3(SS / 32, VCC / 32), 256, 0, stream>>>(acs, acsT, VCC, SS);
    // 14. hc += 0.8 * relu(hs @ acs^T), dual-store hcb bf16 (y12u dead)
    gemm_k<64, 64, 16, 4, 4, true, true, false, true><<<dim3(VCC / 64, MM / 64), 256, 0, stream>>>(
        hs, SS, acsT, VCC, hc, VCC, nullptr, hc, VCC, hcb, SS, 0.8f);
    // 15. hf += 0.2 * relu(hcb @ afc^T) (MFMA, swizzle), dual-store hfb bf16
    gemm_mfma<128, true, true, true, false, true><<<dim3(VV / 128, MM / 128), 256, 0, stream>>>(
        hcb, VCC, afcb, VCC, hf, VV, nullptr, hf, VV, hfb, VCC, 0.2f);
    // 16. hc += 0.2 * relu(hfb @ afc) (MFMA BN=64; B^T = afcTb)
    gemm_mfma<64, false, true, true, false, false><<<dim3(VCC / 64, MM / 128), 256, 0, stream>>>(
        hfb, VV, afcTb, VV, hc, VCC, nullptr, hc, VCC, nullptr, VV, 0.2f);
    // 17. hs += 0.2 * relu(hc @ acs) (fp32, K=256, BM=32: grid (1,192))
    gemm_k<32, 64, 16, 2, 4, true, true, false, false><<<dim3(1, MM / 32), 256, 0, stream>>>(
        hc, VCC, acs, SS, hs, SS, nullptr, hs, SS, nullptr, VCC, 0.2f);
    // 18. node-last -> reference layout [*, node, L]
    transpose_lv<<<dim3(VV / 128, NB * CO), 256, 0, stream>>>(hf, hf_out, VV, 128);
    transpose_lv<<<dim3(VCC / 128, NB * CO), 256, 0, stream>>>(hc, hc_out, VCC, 128);
    transpose_lv<<<dim3(1, NB * CO), 256, 0, stream>>>(hs, hs_out, SS, 64);
}

// Round 10
// 566.218 us; speedup vs baseline: 1.1612x; 1.0442x over previous
//
#include <hip/hip_runtime.h>

// ---------------- problem dims ----------------
constexpr int NB = 16;    // batch
constexpr int CC = 32;    // in channels
constexpr int VV = 2048;  // fine nodes
constexpr int VCC = 256;  // coarse nodes
constexpr int SS = 64;    // super nodes
constexpr int LL = 12;    // time
constexpr int CO = 32;    // out channels
constexpr long MM = (long)NB * CO * LL;  // 6144 rows in node-last layout

typedef __attribute__((ext_vector_type(8))) __bf16 bf16x8;
typedef __attribute__((ext_vector_type(4))) float f32x4;

__device__ __forceinline__ unsigned short f2bf(float f) {
    unsigned u = __float_as_uint(f);
    unsigned r = u + 0x7FFFu + ((u >> 16) & 1u);  // RNE
    return (unsigned short)(r >> 16);
}

__device__ __forceinline__ void gl_lds16(const void* g, void* l) {
    __builtin_amdgcn_global_load_lds(
        (const __attribute__((address_space(1))) void*)g,
        (__attribute__((address_space(3))) void*)l, 16, 0, 0);
}

// =====================================================================
// K1: x [nc, V, 12] -> xt fp32 [nc, 12, V] AND xtb bf16 (same layout)
__global__ __launch_bounds__(256)
void transpose_vl(const float* __restrict__ in, float* __restrict__ out,
                  unsigned short* __restrict__ outb) {
    __shared__ float t[128 * 13];
    const long nc = blockIdx.y;
    const int v0 = blockIdx.x * 128;
    const float* src = in + (nc * VV + v0) * 12;
    for (int f = threadIdx.x; f < 128 * 12; f += 256) {
        const int vv = f / 12, l = f - vv * 12;
        t[vv * 13 + l] = src[f];
    }
    __syncthreads();
    float* dst = out + nc * 12L * VV;
    unsigned short* dstb = outb + nc * 12L * VV;
    for (int g = threadIdx.x; g < 128 * 12; g += 256) {
        int l = g >> 7, vv = g & 127;
        const float v = t[vv * 13 + l];
        dst[(long)l * VV + v0 + vv] = v;
        dstb[(long)l * VV + v0 + vv] = f2bf(v);
    }
}

// out-transpose: in [nc, 12, Kn] -> out [nc, Kn, 12]  (13-pad)
__global__ __launch_bounds__(256)
void transpose_lv(const float* __restrict__ in, float* __restrict__ out, int Kn, int TW) {
    __shared__ float t[128 * 13];
    const long nc = blockIdx.y;
    const int v0 = blockIdx.x * TW;
    const float* src = in + nc * 12L * Kn;
    for (int g = threadIdx.x; g < TW * 12; g += 256) {
        int l = g / TW, vv = g - l * TW;
        t[vv * 13 + l] = src[(long)l * Kn + v0 + vv];
    }
    __syncthreads();
    float* dst = out + (nc * Kn + v0) * 12L;
    for (int f = threadIdx.x; f < TW * 12; f += 256) {
        const int vv = f / 12, l = f - vv * 12;
        dst[f] = t[vv * 13 + l];
    }
}

// small dense fp32 transpose: in [rows, cols] -> out [cols, rows]
__global__ __launch_bounds__(256)
void transpose2d(const float* __restrict__ in, float* __restrict__ out, int rows, int cols) {
    __shared__ float t[32][33];
    const int r0 = blockIdx.y * 32, c0 = blockIdx.x * 32;
    const int ty = threadIdx.x / 32, tx = threadIdx.x % 32;
    for (int i = ty; i < 32; i += 8) t[i][tx] = in[(long)(r0 + i) * cols + c0 + tx];
    __syncthreads();
    for (int i = ty; i < 32; i += 8) out[(long)(c0 + i) * rows + r0 + tx] = t[tx][i];
}

// fp32 [R,C] -> bf16 transpose [C,R]
__global__ __launch_bounds__(256)
void cvt_T_bf16_k(const float* __restrict__ in, unsigned short* __restrict__ out,
                  int R, int Ccols) {
    __shared__ float t[32][33];
    const int r0 = blockIdx.y * 32, c0 = blockIdx.x * 32;
    const int ty = threadIdx.x / 32, tx = threadIdx.x % 32;
    for (int i = ty; i < 32; i += 8) t[i][tx] = in[(long)(r0 + i) * Ccols + c0 + tx];
    __syncthreads();
    for (int i = ty; i < 32; i += 8) out[(long)(c0 + i) * R + r0 + tx] = f2bf(t[tx][i]);
}

// afc [2048,256] fp32 -> afcb bf16 [2048,256] AND afcTb bf16 [256,2048]
__global__ __launch_bounds__(256)
void cvt_afc_both(const float* __restrict__ in, unsigned short* __restrict__ outn,
                  unsigned short* __restrict__ outt) {
    __shared__ float t[32][33];
    const int r0 = blockIdx.y * 32, c0 = blockIdx.x * 32;
    const int ty = threadIdx.x / 32, tx = threadIdx.x % 32;
    for (int i = ty; i < 32; i += 8) {
        const float v = in[(long)(r0 + i) * VCC + c0 + tx];
        t[i][tx] = v;
        outn[(long)(r0 + i) * VCC + c0 + tx] = f2bf(v);
    }
    __syncthreads();
    for (int i = ty; i < 32; i += 8)
        outt[(long)(c0 + i) * VV + r0 + tx] = f2bf(t[tx][i]);
}

// =====================================================================
// fine channel mix: xt [16,32,24576] -> y0 fp32 [M,2048], y12 bf16 [M,4096]
__global__ __launch_bounds__(256)
void chanmix_fine(const float* __restrict__ in, const float* __restrict__ Wt,
                  float* __restrict__ y0, unsigned short* __restrict__ y12) {
    __shared__ float Ws[CO * 96];
    for (int idx = threadIdx.x; idx < CO * 96; idx += 256) Ws[idx] = Wt[idx];
    __syncthreads();
    const int nb = blockIdx.y;
    const int r = blockIdx.x * 256 + threadIdx.x;
    const int R = LL * VV;
    const int l = r / VV, k = r - l * VV;
    float xv[CC];
#pragma unroll
    for (int c = 0; c < CC; ++c) xv[c] = in[((long)(nb * CC + c)) * R + r];
    for (int o = 0; o < CO; ++o) {
        float a0 = 0.f, a1 = 0.f, a2 = 0.f;
#pragma unroll
        for (int c = 0; c < CC; ++c) {
            const float x = xv[c];
            a0 = fmaf(Ws[o * 96 + c], x, a0);
            a1 = fmaf(Ws[o * 96 + 32 + c], x, a1);
            a2 = fmaf(Ws[o * 96 + 64 + c], x, a2);
        }
        const long mrow = (long)(nb * CO + o) * LL + l;
        y0[mrow * VV + k] = a0;
        y12[mrow * 4096 + k] = f2bf(a1);
        y12[mrow * 4096 + 2048 + k] = f2bf(a2);
    }
}

// coarse/super channel mix. o0 fp32 always; o1 fp32 if O1F, o1b bf16 if O1B.
template <bool O1F, bool O1B>
__global__ __launch_bounds__(256)
void chanmix_k(const float* __restrict__ in, const float* __restrict__ Wt,
               int R, int Kn, float* __restrict__ o0,
               float* __restrict__ o1, unsigned short* __restrict__ o1b, int ld1) {
    __shared__ float Ws[CO * 96];
    for (int idx = threadIdx.x; idx < CO * 96; idx += 256) Ws[idx] = Wt[idx];
    __syncthreads();
    const int nb = blockIdx.y;
    const int r = blockIdx.x * 256 + threadIdx.x;
    if (r >= R) return;
    const int l = r / Kn, k = r - l * Kn;
    float xv[CC];
#pragma unroll
    for (int c = 0; c < CC; ++c) xv[c] = in[((long)(nb * CC + c)) * R + r];
    for (int o = 0; o < CO; ++o) {
        float a0 = 0.f, a1 = 0.f, a2 = 0.f;
#pragma unroll
        for (int c = 0; c < CC; ++c) {
            const float x = xv[c];
            a0 = fmaf(Ws[o * 96 + c], x, a0);
            a1 = fmaf(Ws[o * 96 + 32 + c], x, a1);
            a2 = fmaf(Ws[o * 96 + 64 + c], x, a2);
        }
        const long mrow = (long)(nb * CO + o) * LL + l;
        o0[mrow * Kn + k] = a0;
        if constexpr (O1F) {
            o1[mrow * ld1 + k] = a1;
            o1[mrow * ld1 + Kn + k] = a2;
        }
        if constexpr (O1B) {
            o1b[mrow * ld1 + k] = f2bf(a1);
            o1b[mrow * ld1 + Kn + k] = f2bf(a2);
        }
    }
}

// =====================================================================
// bf16 MFMA GEMM: Out[m,n] = (ADDC0? C0[m,n]:0) + (BIAS? bias[(m/12)&31]:0)
//                           + alpha * (RELU? relu(A@B) : A@B)
// A [M,K] bf16 (lda), Bt [N,K] bf16 (ldb) (= B^T). Tile 128xBN, BK=64,
// 4 waves, 16x16x32 MFMA, XOR-swizzled LDS, global_load_lds width-16.
template <int BN, bool SWIZ, bool RELU, bool ADDC0, bool BIAS, bool STB16>
__global__ __launch_bounds__(256)
void gemm_mfma(const unsigned short* __restrict__ A, int lda,
               const unsigned short* __restrict__ Bt, int ldb,
               const float* __restrict__ C0, int ldc,
               const float* __restrict__ bias,
               float* __restrict__ Out, int ldo,
               unsigned short* __restrict__ OutB, int K, float alpha) {
    constexpr int TNT = BN / 32;   // 16-tiles per wave along n (4 or 2)
    constexpr int QB = BN / 32;    // B staging iters (4 or 2)
    constexpr int WN = BN / 2;     // wave n-extent
    __shared__ __align__(16) unsigned short As[128 * 64];
    __shared__ __align__(16) unsigned short Bs[BN * 64];
    const int tid = threadIdx.x;
    const int lane = tid & 63;
    const int w = tid >> 6;

    int pid_m, pid_n;
    if constexpr (SWIZ) {
        const int id = blockIdx.y * gridDim.x + blockIdx.x;
        const int npg = 8 * gridDim.x;
        const int rem = id % npg;
        pid_m = (id / npg) * 8 + (rem & 7);
        pid_n = rem >> 3;
    } else {
        pid_m = blockIdx.y;
        pid_n = blockIdx.x;
    }
    const long m0 = (long)pid_m * 128;
    const int n0 = pid_n * BN;

    long offA[4], offB[QB];
#pragma unroll
    for (int q = 0; q < 4; ++q) {
        const int t = q * 256 + tid;
        const int row = t >> 3, pos = t & 7;
        const int lc = pos ^ (row & 7);
        offA[q] = (m0 + row) * (long)lda + lc * 8;
    }
#pragma unroll
    for (int q = 0; q < QB; ++q) {
        const int t = q * 256 + tid;
        const int row = t >> 3, pos = t & 7;
        const int lc = pos ^ (row & 7);
        offB[q] = (long)(n0 + row) * ldb + lc * 8;
    }
    const int wm = (w & 1) * 64, wn = (w >> 1) * WN;
    const int mrow = lane & 15;
    const int quad = lane >> 4;

    f32x4 acc[4][TNT];
#pragma unroll
    for (int i = 0; i < 4; ++i)
#pragma unroll
        for (int j = 0; j < TNT; ++j) acc[i][j] = (f32x4){0.f, 0.f, 0.f, 0.f};

    for (int k0 = 0; k0 < K; k0 += 64) {
#pragma unroll
        for (int q = 0; q < 4; ++q)
            gl_lds16(A + offA[q] + k0, &As[(q * 256 + w * 64) * 8]);
#pragma unroll
        for (int q = 0; q < QB; ++q)
            gl_lds16(Bt + offB[q] + k0, &Bs[(q * 256 + w * 64) * 8]);
        __syncthreads();
#pragma unroll
        for (int ks = 0; ks < 2; ++ks) {
            bf16x8 af[4], bfr[TNT];
            const int pos = (ks * 4 + quad) ^ (mrow & 7);
#pragma unroll
            for (int tm = 0; tm < 4; ++tm) {
                const int r = wm + tm * 16 + mrow;
                af[tm] = *(const bf16x8*)&As[r * 64 + pos * 8];
            }
#pragma unroll
            for (int tn = 0; tn < TNT; ++tn) {
                const int r = wn + tn * 16 + mrow;
                bfr[tn] = *(const bf16x8*)&Bs[r * 64 + pos * 8];
            }
#pragma unroll
            for (int tm = 0; tm < 4; ++tm)
#pragma unroll
                for (int tn = 0; tn < TNT; ++tn)
                    acc[tm][tn] = __builtin_amdgcn_mfma_f32_16x16x32_bf16(
                        af[tm], bfr[tn], acc[tm][tn], 0, 0, 0);
        }
        __syncthreads();
    }

    // C/D layout: col = lane&15, row = quad*4 + reg
#pragma unroll
    for (int tm = 0; tm < 4; ++tm) {
#pragma unroll
        for (int tn = 0; tn < TNT; ++tn) {
            const int n = n0 + wn + tn * 16 + mrow;
#pragma unroll
            for (int reg = 0; reg < 4; ++reg) {
                const long m = m0 + wm + tm * 16 + quad * 4 + reg;
                float p = acc[tm][tn][reg];
                if (RELU) p = fmaxf(p, 0.f);
                p *= alpha;
                float c = 0.f;
                if constexpr (ADDC0) c = C0[m * (long)ldc + n];
                if (BIAS) c += bias[(int)((m / LL) & (CO - 1))];
                const float res = c + p;
                Out[m * (long)ldo + n] = res;
                if constexpr (STB16) OutB[m * (long)ldo + n] = f2bf(res);
            }
        }
    }
}

// =====================================================================
// 192x256-tile, 8-wave, counted-vmcnt bf16 MFMA GEMM (VERIFIED round-3
// schedule: 108 us, MfmaUtil 40%). Round-5's 4-phase fine-gated variant
// REGRESSED (142 us, m141/m196 order-pinning) -- keep this structure.
// Grid (8,32) = 256 blocks = exact 1-block/CU fill.
__global__ __launch_bounds__(512)
void gemm_mfma256(const unsigned short* __restrict__ A, int lda,
                  const unsigned short* __restrict__ Bt, int ldb,
                  const float* __restrict__ C0, int ldc,
                  const float* __restrict__ bias,
                  float* __restrict__ Out, int ldo, int K) {
    __shared__ __align__(16) unsigned short As[2][192 * 64];
    __shared__ __align__(16) unsigned short Bs[2][256 * 64];
    const int tid = threadIdx.x;
    const int lane = tid & 63;
    const int w = tid >> 6;          // wave 0..7
    const int wr = w >> 2;           // 0..1 : M half (rows wr*96..+95)
    const int wc = w & 3;            // 0..3 : N quarter (cols wc*64..+63)
    const int mrow = lane & 15;
    const int quad = lane >> 4;

    const long m0 = (long)blockIdx.y * 192;
    const int n0 = blockIdx.x * 256;

    long offA[3], offB[4];
#pragma unroll
    for (int q = 0; q < 3; ++q) {
        const int t = q * 512 + tid;
        const int row = t >> 3, pos = t & 7;
        const int lc = pos ^ (row & 7);
        offA[q] = (m0 + row) * (long)lda + lc * 8;
    }
#pragma unroll
    for (int q = 0; q < 4; ++q) {
        const int t = q * 512 + tid;
        const int row = t >> 3, pos = t & 7;
        const int lc = pos ^ (row & 7);
        offB[q] = (long)(n0 + row) * ldb + lc * 8;
    }
    const int NT = K >> 6;

#define STAGE_A(b_, t_)                                                      \
    do {                                                                     \
        gl_lds16(A + offA[0] + (long)(t_) * 64, &As[b_][w * 512]);           \
        gl_lds16(A + offA[1] + (long)(t_) * 64, &As[b_][4096 + w * 512]);    \
        gl_lds16(A + offA[2] + (long)(t_) * 64, &As[b_][8192 + w * 512]);    \
    } while (0)
#define STAGE_B_LO(b_, t_)                                                   \
    do {                                                                     \
        gl_lds16(Bt + offB[0] + (long)(t_) * 64, &Bs[b_][w * 512]);          \
        gl_lds16(Bt + offB[1] + (long)(t_) * 64, &Bs[b_][4096 + w * 512]);   \
    } while (0)
#define STAGE_B_HI(b_, t_)                                                   \
    do {                                                                     \
        gl_lds16(Bt + offB[2] + (long)(t_) * 64, &Bs[b_][8192 + w * 512]);   \
        gl_lds16(Bt + offB[3] + (long)(t_) * 64, &Bs[b_][12288 + w * 512]);  \
    } while (0)

    const int p0 = (quad ^ (mrow & 7)) * 8;           // ks0 chunk
    const int p1 = ((4 + quad) ^ (mrow & 7)) * 8;     // ks1 chunk
    const int ra = (wr * 96 + mrow) * 64;             // + tm*1024
    const int rb = (wc * 64 + mrow) * 64;             // + tn*1024

    f32x4 acc[6][4];
#pragma unroll
    for (int i = 0; i < 6; ++i)
#pragma unroll
        for (int j = 0; j < 4; ++j) acc[i][j] = (f32x4){0.f, 0.f, 0.f, 0.f};

    // prologue: tile0 fully (7 wave-loads), tile1 A + B-lo (5 wave-loads)
    STAGE_A(0, 0); STAGE_B_LO(0, 0); STAGE_B_HI(0, 0);
    if (NT > 1) {
        STAGE_A(1, 1); STAGE_B_LO(1, 1);
        asm volatile("s_waitcnt vmcnt(5)" ::: "memory");  // tile0 landed
    } else {
        asm volatile("s_waitcnt vmcnt(0)" ::: "memory");
    }
    __builtin_amdgcn_sched_barrier(0);
    __builtin_amdgcn_s_barrier();
    __builtin_amdgcn_sched_barrier(0);

    for (int t = 0; t < NT; ++t) {
        const int buf = t & 1;
        bf16x8 a0[6], b0[4], a1[6], b1[4];
#pragma unroll
        for (int tm = 0; tm < 6; ++tm)
            a0[tm] = *(const bf16x8*)&As[buf][ra + tm * 1024 + p0];
#pragma unroll
        for (int tn = 0; tn < 4; ++tn)
            b0[tn] = *(const bf16x8*)&Bs[buf][rb + tn * 1024 + p0];
        if (t + 1 < NT) { STAGE_B_HI(buf ^ 1, t + 1); }  // other buffer: safe
        __builtin_amdgcn_s_setprio(1);
#pragma unroll
        for (int tm = 0; tm < 6; ++tm)
#pragma unroll
            for (int tn = 0; tn < 4; ++tn)
                acc[tm][tn] = __builtin_amdgcn_mfma_f32_16x16x32_bf16(
                    a0[tm], b0[tn], acc[tm][tn], 0, 0, 0);
        __builtin_amdgcn_s_setprio(0);
#pragma unroll
        for (int tm = 0; tm < 6; ++tm)
            a1[tm] = *(const bf16x8*)&As[buf][ra + tm * 1024 + p1];
#pragma unroll
        for (int tn = 0; tn < 4; ++tn)
            b1[tn] = *(const bf16x8*)&Bs[buf][rb + tn * 1024 + p1];
        asm volatile("s_waitcnt lgkmcnt(0)" ::: "memory");  // drain buf reads
        __builtin_amdgcn_sched_barrier(0);
        __builtin_amdgcn_s_barrier();
        __builtin_amdgcn_sched_barrier(0);
        // all waves' reads of buf done -> safe to overwrite with tile t+2
        if (t + 2 < NT) { STAGE_A(buf, t + 2); STAGE_B_LO(buf, t + 2); }
        __builtin_amdgcn_s_setprio(1);
#pragma unroll
        for (int tm = 0; tm < 6; ++tm)
#pragma unroll
            for (int tn = 0; tn < 4; ++tn)
                acc[tm][tn] = __builtin_amdgcn_mfma_f32_16x16x32_bf16(
                    a1[tm], b1[tn], acc[tm][tn], 0, 0, 0);
        __builtin_amdgcn_s_setprio(0);
        if (t + 2 < NT) {
            asm volatile("s_waitcnt vmcnt(5)" ::: "memory");  // tile t+1 landed
        } else if (t + 1 < NT) {
            asm volatile("s_waitcnt vmcnt(0)" ::: "memory");  // tail drain
        }
        __builtin_amdgcn_sched_barrier(0);
        __builtin_amdgcn_s_barrier();
        __builtin_amdgcn_sched_barrier(0);
    }
#undef STAGE_A
#undef STAGE_B_LO
#undef STAGE_B_HI

    // epilogue: C/D layout col = lane&15, row = quad*4 + reg
#pragma unroll
    for (int tm = 0; tm < 6; ++tm) {
#pragma unroll
        for (int tn = 0; tn < 4; ++tn) {
            const int n = n0 + wc * 64 + tn * 16 + mrow;
#pragma unroll
            for (int reg = 0; reg < 4; ++reg) {
                const long m = m0 + wr * 96 + tm * 16 + quad * 4 + reg;
                float p = acc[tm][tn][reg];
                float c = C0[m * (long)ldc + n];
                c += bias[(int)((m / LL) & (CO - 1))];
                Out[m * (long)ldo + n] = c + p;
            }
        }
    }
}

// =====================================================================
// generic fp32 GEMM (narrow / accuracy-critical ops); optional bf16 dual store
template <int BM, int BN, int BK, int TM, int TN, bool RELU, bool ADDC0, bool BIAS, bool STB16>
__global__ __launch_bounds__(256)
void gemm_k(const float* __restrict__ X, int ldx,
            const float* __restrict__ Bm, int ldb,
            const float* __restrict__ C0, int ldc,
            const float* __restrict__ bias,
            float* __restrict__ Out, int ldo,
            unsigned short* __restrict__ outb, int K, float alpha) {
    constexpr int TX = BN / TN;
    constexpr int LX = (BM * BK) / 256;
    constexpr int LB = (BN * BK) / 256;
    __shared__ float Xs[BK][BM + 4];
    __shared__ float Bs[BK][BN + 4];
    const int tid = threadIdx.x;
    const int tx = tid % TX, ty = tid / TX;
    const long m0 = (long)blockIdx.y * BM;
    const int n0 = blockIdx.x * BN;
    const int xr = tid / (BK / LX);
    const int xcc = (tid % (BK / LX)) * LX;
    const int br = tid / (BN / LB);
    const int bc = (tid % (BN / LB)) * LB;

    float acc[TM][TN];
#pragma unroll
    for (int i = 0; i < TM; ++i)
#pragma unroll
        for (int j = 0; j < TN; ++j) acc[i][j] = 0.f;

    const float* Xp = X + (m0 + xr) * (long)ldx + xcc;
    const float* Bp = Bm + (long)br * ldb + n0 + bc;

    for (int k0 = 0; k0 < K; k0 += BK) {
        if constexpr (LX == 4) {
            const float4 v = *(const float4*)Xp;
            Xs[xcc + 0][xr] = v.x; Xs[xcc + 1][xr] = v.y;
            Xs[xcc + 2][xr] = v.z; Xs[xcc + 3][xr] = v.w;
        } else {
            const float2 v = *(const float2*)Xp;
            Xs[xcc + 0][xr] = v.x; Xs[xcc + 1][xr] = v.y;
        }
        if constexpr (LB == 4) {
            *(float4*)&Bs[br][bc] = *(const float4*)Bp;
        } else {
            *(float2*)&Bs[br][bc] = *(const float2*)Bp;
        }
        __syncthreads();
#pragma unroll
        for (int kk = 0; kk < BK; ++kk) {
            float a[TM], b[TN];
#pragma unroll
            for (int i = 0; i < TM; ++i) a[i] = Xs[kk][ty * TM + i];
#pragma unroll
            for (int j = 0; j < TN; ++j) b[j] = Bs[kk][tx * TN + j];
#pragma unroll
            for (int i = 0; i < TM; ++i)
#pragma unroll
                for (int j = 0; j < TN; ++j) acc[i][j] = fmaf(a[i], b[j], acc[i][j]);
        }
        __syncthreads();
        Xp += BK;
        Bp += (long)BK * ldb;
    }

#pragma unroll
    for (int i = 0; i < TM; ++i) {
        const long m = m0 + (long)ty * TM + i;
        float bv = 0.f;
        if (BIAS) bv = bias[(int)((m / LL) & (CO - 1))];
        const long obase = m * (long)ldo + n0 + tx * TN;
        long cbase = 0;
        if constexpr (ADDC0) cbase = m * (long)ldc + n0 + tx * TN;
#pragma unroll
        for (int j = 0; j < TN; ++j) {
            float p = acc[i][j];
            if (RELU) p = fmaxf(p, 0.f);
            p *= alpha;
            float c = 0.f;
            if constexpr (ADDC0) c = C0[cbase + j];
            const float res = c + p + bv;
            Out[obase + j] = res;
            if constexpr (STB16) outb[obase + j] = f2bf(res);
        }
    }
}

// =====================================================================
__global__ __launch_bounds__(256)
void zero_k(float* __restrict__ p, int n) {
    for (int i = blockIdx.x * 256 + threadIdx.x; i < n; i += gridDim.x * 256) p[i] = 0.f;
}

// split-K Gram with mismatched flatten orders (faithful)
__global__ __launch_bounds__(256)
void asmat_split(const float* __restrict__ sxg, float* __restrict__ am_raw) {
    __shared__ float Us[128][65];
    __shared__ float Wsh[128][65];
    __shared__ int rA[128], rB[128];
    const int i0 = blockIdx.x * 128;
    const int tid = threadIdx.x;
    if (tid < 128) {
        const int i = i0 + tid;
        const int c = i / 192;
        const int rem = i - c * 192;
        const int n = rem / 12;
        const int l = rem - n * 12;
        rA[tid] = (n * 32 + c) * 12 + l;
        const int l2 = i >> 9;
        const int rem2 = i & 511;
        rB[tid] = ((rem2 >> 5) * 32 + (rem2 & 31)) * 12 + l2;
    }
    __syncthreads();
    for (int idx = tid; idx < 128 * 64; idx += 256) {
        const int r = idx >> 6, s = idx & 63;
        Us[r][s] = sxg[rA[r] * 64 + s];
        Wsh[r][s] = sxg[rB[r] * 64 + s];
    }
    __syncthreads();
    const int ts = (tid & 15) * 4;
    const int tt = (tid >> 4) * 4;
    float acc[4][4];
#pragma unroll
    for (int i2 = 0; i2 < 4; ++i2)
#pragma unroll
        for (int j = 0; j < 4; ++j) acc[i2][j] = 0.f;
    for (int k = 0; k < 128; ++k) {
        float a[4], bv[4];
#pragma unroll
        for (int i2 = 0; i2 < 4; ++i2) a[i2] = Us[k][ts + i2];
#pragma unroll
        for (int j = 0; j < 4; ++j) bv[j] = Wsh[k][tt + j];
#pragma unroll
        for (int i2 = 0; i2 < 4; ++i2)
#pragma unroll
            for (int j = 0; j < 4; ++j) acc[i2][j] = fmaf(a[i2], bv[j], acc[i2][j]);
    }
#pragma unroll
    for (int i2 = 0; i2 < 4; ++i2)
#pragma unroll
        for (int j = 0; j < 4; ++j)
            atomicAdd(&am_raw[(ts + i2) * 64 + tt + j], acc[i2][j]);
}

// sup[0] = softmax(rownorm(relu(raw-0.5))), sup[1] = same on transpose
__global__ __launch_bounds__(64)
void supbuild_k(const float* __restrict__ am_raw, float* __restrict__ sup) {
    __shared__ float a[64][65];
    for (int idx = threadIdx.x; idx < 4096; idx += 64) {
        const float v = am_raw[idx] - 0.5f;
        a[idx >> 6][idx & 63] = v > 0.f ? v : 0.f;
    }
    __syncthreads();
    const int r = threadIdx.x;
    {
        float rs = 0.f;
        for (int j = 0; j < 64; ++j) rs += a[r][j];
        const float dinv = rs > 0.f ? 1.f / rs : 0.f;
        float mx = -1e30f;
        for (int j = 0; j < 64; ++j) mx = fmaxf(mx, a[r][j] * dinv);
        float se = 0.f;
        for (int j = 0; j < 64; ++j) se += expf(a[r][j] * dinv - mx);
        const float inv = 1.f / se;
        for (int j = 0; j < 64; ++j) sup[r * 64 + j] = expf(a[r][j] * dinv - mx) * inv;
    }
    {
        float rs = 0.f;
        for (int j = 0; j < 64; ++j) rs += a[j][r];
        const float dinv = rs > 0.f ? 1.f / rs : 0.f;
        float mx = -1e30f;
        for (int j = 0; j < 64; ++j) mx = fmaxf(mx, a[j][r] * dinv);
        float se = 0.f;
        for (int j = 0; j < 64; ++j) se += expf(a[j][r] * dinv - mx);
        const float inv = 1.f / se;
        for (int j = 0; j < 64; ++j) sup[4096 + r * 64 + j] = expf(a[j][r] * dinv - mx) * inv;
    }
}

// =====================================================================
extern "C" void kernel_launch(void* const* d_in, const int* in_sizes, int n_in,
                              void* d_out, int out_size, void* d_ws, size_t ws_size,
                              hipStream_t stream) {
    (void)in_sizes; (void)n_in; (void)out_size; (void)ws_size;
    const float* x    = (const float*)d_in[0];
    const float* sup  = (const float*)d_in[1];  // [2, V, V]
    const float* supc = (const float*)d_in[2];  // [2, VC, VC]
    const float* acs  = (const float*)d_in[3];  // [VC, S]
    const float* afc  = (const float*)d_in[4];  // [V, VC]
    const float* W    = (const float*)d_in[5];  // [32, 96]
    const float* b    = (const float*)d_in[6];  // [32]
    float* ws = (float*)d_ws;

    // --- region A [0, 12,582,912): xt fp32 (alive steps 1-4); then reused:
    // (NOTE round-9 bug: supcTb was written at step 2b, INSIDE xt's live
    //  range, corrupting xt before chanmix_fine read it -> absmax 0.78.
    //  Fixed: supcTb conversion now runs AFTER step 4.)
    float* xt = ws;
    unsigned short* Btu = (unsigned short*)ws;                // bf16 [2048][4096], from step 5
    float* yc0  = ws + 4456448;
    unsigned short* yc12b = (unsigned short*)(ws + 6029312);  // bf16 [6144][512] (old yc12 slot)
    unsigned short* supcTb = (unsigned short*)(ws + 7602176); // bf16 [256][512], from step 5a
    float* ys0  = ws + 9175040;
    float* ys12 = ws + 9568256;
    float* hc   = ws + 10354688;
    float* hs   = ws + 11927552;
    float* am   = ws + 12320768;
    float* sups = ws + 12324864;
    float* acsT = ws + 12333056;                              // ends 12,349,440
    // --- fixed regions
    float* hf   = ws + 12582912;                              // y0 then hf
    float* xc   = ws + 25165824;
    float* sxg  = ws + 26738688;
    unsigned short* afcTb = (unsigned short*)(ws + 27131904); // bf16 [256][2048]
    unsigned short* afcb  = (unsigned short*)(ws + 27394048); // bf16 [2048][256]
    // ws total 27,656,192 floats (~110.6 MB)

    // --- d_out doubles as scratch (dead before final output writes)
    float* out_f = (float*)d_out;
    unsigned short* xtb  = (unsigned short*)d_out;            // bf16 [6144][2048], steps 1-3
    unsigned short* y12u = (unsigned short*)d_out;            // bf16 [6144][4096], steps 4-11
    unsigned short* hfb  = (unsigned short*)d_out;            // bf16 [6144][2048], steps 15-19
    unsigned short* hcb  = ((unsigned short*)d_out) + 12582912;  // bf16 [6144][256]
    float* hf_out = out_f;
    float* hc_out = out_f + 12582912;
    float* hs_out = out_f + 14155776;

    // 1. xt = transpose(x) (+ bf16 copy xtb into d_out)
    transpose_vl<<<dim3(VV / 128, NB * CC), 256, 0, stream>>>(x, xt, xtb);
    // 2. afcb + afcTb in one pass (ws tail - outside xt region)
    cvt_afc_both<<<dim3(VCC / 32, VV / 32), 256, 0, stream>>>(afc, afcb, afcTb);
    // 3. xc = xtb @ afc  (MFMA BN=64; B^T = afcTb)
    gemm_mfma<64, false, false, false, false, false><<<dim3(VCC / 64, MM / 128), 256, 0, stream>>>(
        xtb, VV, afcTb, VV, nullptr, 0, nullptr, xc, VCC, nullptr, VV, 1.0f);
    // 4. fine chanmix: y0 -> hf (fp32), y12 -> d_out (bf16; clobbers xtb - dead)
    chanmix_fine<<<dim3(96, 16), 256, 0, stream>>>(xt, W, hf, y12u);
    // 5a. supcTb = bf16([Ac1;Ac2]^T) [256][512] -- AFTER step 4 (xt now dead)
    cvt_T_bf16_k<<<dim3(VCC / 32, 2 * VCC / 32), 256, 0, stream>>>(supc, supcTb, 2 * VCC, VCC);
    // 5. Btu = bf16([A1;A2]^T) [2048][4096]  (region A; xt dead after step 4)
    cvt_T_bf16_k<<<dim3(VV / 32, 2 * VV / 32), 256, 0, stream>>>(sup, Btu, 2 * VV, VV);
    // 6. sxg = xc @ acs (fp32, BM=32: grid (1,192))
    gemm_k<32, 64, 16, 2, 4, false, false, false, false><<<dim3(1, MM / 32), 256, 0, stream>>>(
        xc, VCC, acs, SS, nullptr, 0, nullptr, sxg, SS, nullptr, VCC, 1.0f);
    // 7. coarse chanmix: yc0 fp32 + yc12b bf16 (fp32 o1 dropped - only MFMA consumes it)
    chanmix_k<false, true><<<dim3(12, 16), 256, 0, stream>>>(
        xc, W, LL * VCC, VCC, yc0, nullptr, yc12b, 2 * VCC);
    // 8. super chanmix (fp32 o1 kept - step 12 stays fp32)
    chanmix_k<true, false><<<dim3(3, 16), 256, 0, stream>>>(
        sxg, W, LL * SS, SS, ys0, ys12, nullptr, 2 * SS);
    // 9. gram + supports
    zero_k<<<dim3(4), 256, 0, stream>>>(am, 4096);
    asmat_split<<<dim3(48), 256, 0, stream>>>(sxg, am);
    supbuild_k<<<dim3(1), 64, 0, stream>>>(am, sups);
    // 10. K3 (192x256 8-wave counted-vmcnt MFMA, round-3 schedule):
    //     hf = y0 + y12 @ [A1;A2] + bias. grid (8,32)=256 blocks.
    gemm_mfma256<<<dim3(VV / 256, MM / 192), 512, 0, stream>>>(
        y12u, 4096, Btu, 4096, hf, VV, b, hf, VV, 4096);
    // 11. hc = yc0 + yc12 @ [Ac1;Ac2] + bias  (bf16 MFMA, K=512; same
    //     structure as the fine path step 10)
    gemm_mfma<64, false, false, true, true, false><<<dim3(VCC / 64, MM / 128), 256, 0, stream>>>(
        yc12b, 2 * VCC, supcTb, 2 * VCC, yc0, VCC, b, hc, VCC, nullptr, 2 * VCC, 1.0f);
    // 12. hs = ys0 + ys12 @ [As1;As2] + bias (fp32, BM=32: grid (1,192))
    gemm_k<32, 64, 16, 2, 4, false, true, true, false><<<dim3(1, MM / 32), 256, 0, stream>>>(
        ys12, 2 * SS, sups, SS, ys0, SS, b, hs, SS, nullptr, 2 * SS, 1.0f);
    // 13. acsT (fp32)
    transpose2d<<<dim3(SS / 32, VCC / 32), 256, 0, stream>>>(acs, acsT, VCC, SS);
    // 14. hc += 0.8 * relu(hs @ acs^T), dual-store hcb bf16 (y12u dead)
    gemm_k<64, 64, 16, 4, 4, true, true, false, true><<<dim3(VCC / 64, MM / 64), 256, 0, stream>>>(
        hs, SS, acsT, VCC, hc, VCC, nullptr, hc, VCC, hcb, SS, 0.8f);
    // 15. hf += 0.2 * relu(hcb @ afc^T) (MFMA, swizzle), dual-store hfb bf16
    gemm_mfma<128, true, true, true, false, true><<<dim3(VV / 128, MM / 128), 256, 0, stream>>>(
        hcb, VCC, afcb, VCC, hf, VV, nullptr, hf, VV, hfb, VCC, 0.2f);
    // 16. hc += 0.2 * relu(hfb @ afc) (MFMA BN=64; B^T = afcTb)
    gemm_mfma<64, false, true, true, false, false><<<dim3(VCC / 64, MM / 128), 256, 0, stream>>>(
        hfb, VV, afcTb, VV, hc, VCC, nullptr, hc, VCC, nullptr, VV, 0.2f);
    // 17. hs += 0.2 * relu(hc @ acs) (fp32, K=256, BM=32: grid (1,192))
    gemm_k<32, 64, 16, 2, 4, true, true, false, false><<<dim3(1, MM / 32), 256, 0, stream>>>(
        hc, VCC, acs, SS, hs, SS, nullptr, hs, SS, nullptr, VCC, 0.2f);
    // 18. node-last -> reference layout [*, node, L]
    transpose_lv<<<dim3(VV / 128, NB * CO), 256, 0, stream>>>(hf, hf_out, VV, 128);
    transpose_lv<<<dim3(VCC / 128, NB * CO), 256, 0, stream>>>(hc, hc_out, VCC, 128);
    transpose_lv<<<dim3(1, NB * CO), 256, 0, stream>>>(hs, hs_out, SS, 64);
}

// Round 11
// 564.984 us; speedup vs baseline: 1.1638x; 1.0022x over previous
//
#include <hip/hip_runtime.h>

// ---------------- problem dims ----------------
constexpr int NB = 16;    // batch
constexpr int CC = 32;    // in channels
constexpr int VV = 2048;  // fine nodes
constexpr int VCC = 256;  // coarse nodes
constexpr int SS = 64;    // super nodes
constexpr int LL = 12;    // time
constexpr int CO = 32;    // out channels
constexpr long MM = (long)NB * CO * LL;  // 6144 rows in node-last layout

typedef __attribute__((ext_vector_type(8))) __bf16 bf16x8;
typedef __attribute__((ext_vector_type(4))) float f32x4;

__device__ __forceinline__ unsigned short f2bf(float f) {
    unsigned u = __float_as_uint(f);
    unsigned r = u + 0x7FFFu + ((u >> 16) & 1u);  // RNE
    return (unsigned short)(r >> 16);
}

__device__ __forceinline__ void gl_lds16(const void* g, void* l) {
    __builtin_amdgcn_global_load_lds(
        (const __attribute__((address_space(1))) void*)g,
        (__attribute__((address_space(3))) void*)l, 16, 0, 0);
}

// =====================================================================
// K1: x [nc, V, 12] -> xt fp32 [nc, 12, V] AND xtb bf16 (same layout)
__global__ __launch_bounds__(256)
void transpose_vl(const float* __restrict__ in, float* __restrict__ out,
                  unsigned short* __restrict__ outb) {
    __shared__ float t[128 * 13];
    const long nc = blockIdx.y;
    const int v0 = blockIdx.x * 128;
    const float* src = in + (nc * VV + v0) * 12;
    for (int f = threadIdx.x; f < 128 * 12; f += 256) {
        const int vv = f / 12, l = f - vv * 12;
        t[vv * 13 + l] = src[f];
    }
    __syncthreads();
    float* dst = out + nc * 12L * VV;
    unsigned short* dstb = outb + nc * 12L * VV;
    for (int g = threadIdx.x; g < 128 * 12; g += 256) {
        int l = g >> 7, vv = g & 127;
        const float v = t[vv * 13 + l];
        dst[(long)l * VV + v0 + vv] = v;
        dstb[(long)l * VV + v0 + vv] = f2bf(v);
    }
}

// out-transpose: in [nc, 12, Kn] -> out [nc, Kn, 12]  (13-pad)
__global__ __launch_bounds__(256)
void transpose_lv(const float* __restrict__ in, float* __restrict__ out, int Kn, int TW) {
    __shared__ float t[128 * 13];
    const long nc = blockIdx.y;
    const int v0 = blockIdx.x * TW;
    const float* src = in + nc * 12L * Kn;
    for (int g = threadIdx.x; g < TW * 12; g += 256) {
        int l = g / TW, vv = g - l * TW;
        t[vv * 13 + l] = src[(long)l * Kn + v0 + vv];
    }
    __syncthreads();
    float* dst = out + (nc * Kn + v0) * 12L;
    for (int f = threadIdx.x; f < TW * 12; f += 256) {
        const int vv = f / 12, l = f - vv * 12;
        dst[f] = t[vv * 13 + l];
    }
}

// fp32 [R,C] -> bf16 transpose [C,R]
__global__ __launch_bounds__(256)
void cvt_T_bf16_k(const float* __restrict__ in, unsigned short* __restrict__ out,
                  int R, int Ccols) {
    __shared__ float t[32][33];
    const int r0 = blockIdx.y * 32, c0 = blockIdx.x * 32;
    const int ty = threadIdx.x / 32, tx = threadIdx.x % 32;
    for (int i = ty; i < 32; i += 8) t[i][tx] = in[(long)(r0 + i) * Ccols + c0 + tx];
    __syncthreads();
    for (int i = ty; i < 32; i += 8) out[(long)(c0 + i) * R + r0 + tx] = f2bf(t[tx][i]);
}

// elementwise fp32 -> bf16
__global__ __launch_bounds__(256)
void cvt_bf16_k(const float* __restrict__ in, unsigned short* __restrict__ out, int n) {
    for (int i = blockIdx.x * 256 + threadIdx.x; i < n; i += gridDim.x * 256)
        out[i] = f2bf(in[i]);
}

// afc [2048,256] fp32 -> afcb bf16 [2048,256] AND afcTb bf16 [256,2048]
__global__ __launch_bounds__(256)
void cvt_afc_both(const float* __restrict__ in, unsigned short* __restrict__ outn,
                  unsigned short* __restrict__ outt) {
    __shared__ float t[32][33];
    const int r0 = blockIdx.y * 32, c0 = blockIdx.x * 32;
    const int ty = threadIdx.x / 32, tx = threadIdx.x % 32;
    for (int i = ty; i < 32; i += 8) {
        const float v = in[(long)(r0 + i) * VCC + c0 + tx];
        t[i][tx] = v;
        outn[(long)(r0 + i) * VCC + c0 + tx] = f2bf(v);
    }
    __syncthreads();
    for (int i = ty; i < 32; i += 8)
        outt[(long)(c0 + i) * VV + r0 + tx] = f2bf(t[tx][i]);
}

// =====================================================================
// fine channel mix: xt [16,32,24576] -> y0 fp32 [M,2048], y12 bf16 [M,4096]
__global__ __launch_bounds__(256)
void chanmix_fine(const float* __restrict__ in, const float* __restrict__ Wt,
                  float* __restrict__ y0, unsigned short* __restrict__ y12) {
    __shared__ float Ws[CO * 96];
    for (int idx = threadIdx.x; idx < CO * 96; idx += 256) Ws[idx] = Wt[idx];
    __syncthreads();
    const int nb = blockIdx.y;
    const int r = blockIdx.x * 256 + threadIdx.x;
    const int R = LL * VV;
    const int l = r / VV, k = r - l * VV;
    float xv[CC];
#pragma unroll
    for (int c = 0; c < CC; ++c) xv[c] = in[((long)(nb * CC + c)) * R + r];
    for (int o = 0; o < CO; ++o) {
        float a0 = 0.f, a1 = 0.f, a2 = 0.f;
#pragma unroll
        for (int c = 0; c < CC; ++c) {
            const float x = xv[c];
            a0 = fmaf(Ws[o * 96 + c], x, a0);
            a1 = fmaf(Ws[o * 96 + 32 + c], x, a1);
            a2 = fmaf(Ws[o * 96 + 64 + c], x, a2);
        }
        const long mrow = (long)(nb * CO + o) * LL + l;
        y0[mrow * VV + k] = a0;
        y12[mrow * 4096 + k] = f2bf(a1);
        y12[mrow * 4096 + 2048 + k] = f2bf(a2);
    }
}

// coarse/super channel mix. o0 fp32 always; o1 fp32 if O1F, o1b bf16 if O1B.
template <bool O1F, bool O1B>
__global__ __launch_bounds__(256)
void chanmix_k(const float* __restrict__ in, const float* __restrict__ Wt,
               int R, int Kn, float* __restrict__ o0,
               float* __restrict__ o1, unsigned short* __restrict__ o1b, int ld1) {
    __shared__ float Ws[CO * 96];
    for (int idx = threadIdx.x; idx < CO * 96; idx += 256) Ws[idx] = Wt[idx];
    __syncthreads();
    const int nb = blockIdx.y;
    const int r = blockIdx.x * 256 + threadIdx.x;
    if (r >= R) return;
    const int l = r / Kn, k = r - l * Kn;
    float xv[CC];
#pragma unroll
    for (int c = 0; c < CC; ++c) xv[c] = in[((long)(nb * CC + c)) * R + r];
    for (int o = 0; o < CO; ++o) {
        float a0 = 0.f, a1 = 0.f, a2 = 0.f;
#pragma unroll
        for (int c = 0; c < CC; ++c) {
            const float x = xv[c];
            a0 = fmaf(Ws[o * 96 + c], x, a0);
            a1 = fmaf(Ws[o * 96 + 32 + c], x, a1);
            a2 = fmaf(Ws[o * 96 + 64 + c], x, a2);
        }
        const long mrow = (long)(nb * CO + o) * LL + l;
        o0[mrow * Kn + k] = a0;
        if constexpr (O1F) {
            o1[mrow * ld1 + k] = a1;
            o1[mrow * ld1 + Kn + k] = a2;
        }
        if constexpr (O1B) {
            o1b[mrow * ld1 + k] = f2bf(a1);
            o1b[mrow * ld1 + Kn + k] = f2bf(a2);
        }
    }
}

// =====================================================================
// bf16 MFMA GEMM: Out[m,n] = (ADDC0? C0[m,n]:0) + (BIAS? bias[(m/12)&31]:0)
//                           + alpha * (RELU? relu(A@B) : A@B)
// A [M,K] bf16 (lda), Bt [N,K] bf16 (ldb) (= B^T). Tile 128xBN, BK=64,
// 4 waves, 16x16x32 MFMA, XOR-swizzled LDS, global_load_lds width-16.
template <int BN, bool SWIZ, bool RELU, bool ADDC0, bool BIAS, bool STB16>
__global__ __launch_bounds__(256)
void gemm_mfma(const unsigned short* __restrict__ A, int lda,
               const unsigned short* __restrict__ Bt, int ldb,
               const float* __restrict__ C0, int ldc,
               const float* __restrict__ bias,
               float* __restrict__ Out, int ldo,
               unsigned short* __restrict__ OutB, int K, float alpha) {
    constexpr int TNT = BN / 32;   // 16-tiles per wave along n (4 or 2)
    constexpr int QB = BN / 32;    // B staging iters (4 or 2)
    constexpr int WN = BN / 2;     // wave n-extent
    __shared__ __align__(16) unsigned short As[128 * 64];
    __shared__ __align__(16) unsigned short Bs[BN * 64];
    const int tid = threadIdx.x;
    const int lane = tid & 63;
    const int w = tid >> 6;

    int pid_m, pid_n;
    if constexpr (SWIZ) {
        const int id = blockIdx.y * gridDim.x + blockIdx.x;
        const int npg = 8 * gridDim.x;
        const int rem = id % npg;
        pid_m = (id / npg) * 8 + (rem & 7);
        pid_n = rem >> 3;
    } else {
        pid_m = blockIdx.y;
        pid_n = blockIdx.x;
    }
    const long m0 = (long)pid_m * 128;
    const int n0 = pid_n * BN;

    long offA[4], offB[QB];
#pragma unroll
    for (int q = 0; q < 4; ++q) {
        const int t = q * 256 + tid;
        const int row = t >> 3, pos = t & 7;
        const int lc = pos ^ (row & 7);
        offA[q] = (m0 + row) * (long)lda + lc * 8;
    }
#pragma unroll
    for (int q = 0; q < QB; ++q) {
        const int t = q * 256 + tid;
        const int row = t >> 3, pos = t & 7;
        const int lc = pos ^ (row & 7);
        offB[q] = (long)(n0 + row) * ldb + lc * 8;
    }
    const int wm = (w & 1) * 64, wn = (w >> 1) * WN;
    const int mrow = lane & 15;
    const int quad = lane >> 4;

    f32x4 acc[4][TNT];
#pragma unroll
    for (int i = 0; i < 4; ++i)
#pragma unroll
        for (int j = 0; j < TNT; ++j) acc[i][j] = (f32x4){0.f, 0.f, 0.f, 0.f};

    for (int k0 = 0; k0 < K; k0 += 64) {
#pragma unroll
        for (int q = 0; q < 4; ++q)
            gl_lds16(A + offA[q] + k0, &As[(q * 256 + w * 64) * 8]);
#pragma unroll
        for (int q = 0; q < QB; ++q)
            gl_lds16(Bt + offB[q] + k0, &Bs[(q * 256 + w * 64) * 8]);
        __syncthreads();
#pragma unroll
        for (int ks = 0; ks < 2; ++ks) {
            bf16x8 af[4], bfr[TNT];
            const int pos = (ks * 4 + quad) ^ (mrow & 7);
#pragma unroll
            for (int tm = 0; tm < 4; ++tm) {
                const int r = wm + tm * 16 + mrow;
                af[tm] = *(const bf16x8*)&As[r * 64 + pos * 8];
            }
#pragma unroll
            for (int tn = 0; tn < TNT; ++tn) {
                const int r = wn + tn * 16 + mrow;
                bfr[tn] = *(const bf16x8*)&Bs[r * 64 + pos * 8];
            }
#pragma unroll
            for (int tm = 0; tm < 4; ++tm)
#pragma unroll
                for (int tn = 0; tn < TNT; ++tn)
                    acc[tm][tn] = __builtin_amdgcn_mfma_f32_16x16x32_bf16(
                        af[tm], bfr[tn], acc[tm][tn], 0, 0, 0);
        }
        __syncthreads();
    }

    // C/D layout: col = lane&15, row = quad*4 + reg
#pragma unroll
    for (int tm = 0; tm < 4; ++tm) {
#pragma unroll
        for (int tn = 0; tn < TNT; ++tn) {
            const int n = n0 + wn + tn * 16 + mrow;
#pragma unroll
            for (int reg = 0; reg < 4; ++reg) {
                const long m = m0 + wm + tm * 16 + quad * 4 + reg;
                float p = acc[tm][tn][reg];
                if (RELU) p = fmaxf(p, 0.f);
                p *= alpha;
                float c = 0.f;
                if constexpr (ADDC0) c = C0[m * (long)ldc + n];
                if (BIAS) c += bias[(int)((m / LL) & (CO - 1))];
                const float res = c + p;
                Out[m * (long)ldo + n] = res;
                if constexpr (STB16) OutB[m * (long)ldo + n] = f2bf(res);
            }
        }
    }
}

// =====================================================================
// 192x256-tile, 8-wave, counted-vmcnt bf16 MFMA GEMM (VERIFIED round-3
// schedule: 108 us, MfmaUtil 40%). Round-5's 4-phase fine-gated variant
// REGRESSED (142 us, m141/m196 order-pinning) -- keep this structure.
// Grid (8,32) = 256 blocks = exact 1-block/CU fill.
__global__ __launch_bounds__(512)
void gemm_mfma256(const unsigned short* __restrict__ A, int lda,
                  const unsigned short* __restrict__ Bt, int ldb,
                  const float* __restrict__ C0, int ldc,
                  const float* __restrict__ bias,
                  float* __restrict__ Out, int ldo, int K) {
    __shared__ __align__(16) unsigned short As[2][192 * 64];
    __shared__ __align__(16) unsigned short Bs[2][256 * 64];
    const int tid = threadIdx.x;
    const int lane = tid & 63;
    const int w = tid >> 6;          // wave 0..7
    const int wr = w >> 2;           // 0..1 : M half (rows wr*96..+95)
    const int wc = w & 3;            // 0..3 : N quarter (cols wc*64..+63)
    const int mrow = lane & 15;
    const int quad = lane >> 4;

    const long m0 = (long)blockIdx.y * 192;
    const int n0 = blockIdx.x * 256;

    long offA[3], offB[4];
#pragma unroll
    for (int q = 0; q < 3; ++q) {
        const int t = q * 512 + tid;
        const int row = t >> 3, pos = t & 7;
        const int lc = pos ^ (row & 7);
        offA[q] = (m0 + row) * (long)lda + lc * 8;
    }
#pragma unroll
    for (int q = 0; q < 4; ++q) {
        const int t = q * 512 + tid;
        const int row = t >> 3, pos = t & 7;
        const int lc = pos ^ (row & 7);
        offB[q] = (long)(n0 + row) * ldb + lc * 8;
    }
    const int NT = K >> 6;

#define STAGE_A(b_, t_)                                                      \
    do {                                                                     \
        gl_lds16(A + offA[0] + (long)(t_) * 64, &As[b_][w * 512]);           \
        gl_lds16(A + offA[1] + (long)(t_) * 64, &As[b_][4096 + w * 512]);    \
        gl_lds16(A + offA[2] + (long)(t_) * 64, &As[b_][8192 + w * 512]);    \
    } while (0)
#define STAGE_B_LO(b_, t_)                                                   \
    do {                                                                     \
        gl_lds16(Bt + offB[0] + (long)(t_) * 64, &Bs[b_][w * 512]);          \
        gl_lds16(Bt + offB[1] + (long)(t_) * 64, &Bs[b_][4096 + w * 512]);   \
    } while (0)
#define STAGE_B_HI(b_, t_)                                                   \
    do {                                                                     \
        gl_lds16(Bt + offB[2] + (long)(t_) * 64, &Bs[b_][8192 + w * 512]);   \
        gl_lds16(Bt + offB[3] + (long)(t_) * 64, &Bs[b_][12288 + w * 512]);  \
    } while (0)

    const int p0 = (quad ^ (mrow & 7)) * 8;           // ks0 chunk
    const int p1 = ((4 + quad) ^ (mrow & 7)) * 8;     // ks1 chunk
    const int ra = (wr * 96 + mrow) * 64;             // + tm*1024
    const int rb = (wc * 64 + mrow) * 64;             // + tn*1024

    f32x4 acc[6][4];
#pragma unroll
    for (int i = 0; i < 6; ++i)
#pragma unroll
        for (int j = 0; j < 4; ++j) acc[i][j] = (f32x4){0.f, 0.f, 0.f, 0.f};

    // prologue: tile0 fully (7 wave-loads), tile1 A + B-lo (5 wave-loads)
    STAGE_A(0, 0); STAGE_B_LO(0, 0); STAGE_B_HI(0, 0);
    if (NT > 1) {
        STAGE_A(1, 1); STAGE_B_LO(1, 1);
        asm volatile("s_waitcnt vmcnt(5)" ::: "memory");  // tile0 landed
    } else {
        asm volatile("s_waitcnt vmcnt(0)" ::: "memory");
    }
    __builtin_amdgcn_sched_barrier(0);
    __builtin_amdgcn_s_barrier();
    __builtin_amdgcn_sched_barrier(0);

    for (int t = 0; t < NT; ++t) {
        const int buf = t & 1;
        bf16x8 a0[6], b0[4], a1[6], b1[4];
#pragma unroll
        for (int tm = 0; tm < 6; ++tm)
            a0[tm] = *(const bf16x8*)&As[buf][ra + tm * 1024 + p0];
#pragma unroll
        for (int tn = 0; tn < 4; ++tn)
            b0[tn] = *(const bf16x8*)&Bs[buf][rb + tn * 1024 + p0];
        if (t + 1 < NT) { STAGE_B_HI(buf ^ 1, t + 1); }  // other buffer: safe
        __builtin_amdgcn_s_setprio(1);
#pragma unroll
        for (int tm = 0; tm < 6; ++tm)
#pragma unroll
            for (int tn = 0; tn < 4; ++tn)
                acc[tm][tn] = __builtin_amdgcn_mfma_f32_16x16x32_bf16(
                    a0[tm], b0[tn], acc[tm][tn], 0, 0, 0);
        __builtin_amdgcn_s_setprio(0);
#pragma unroll
        for (int tm = 0; tm < 6; ++tm)
            a1[tm] = *(const bf16x8*)&As[buf][ra + tm * 1024 + p1];
#pragma unroll
        for (int tn = 0; tn < 4; ++tn)
            b1[tn] = *(const bf16x8*)&Bs[buf][rb + tn * 1024 + p1];
        asm volatile("s_waitcnt lgkmcnt(0)" ::: "memory");  // drain buf reads
        __builtin_amdgcn_sched_barrier(0);
        __builtin_amdgcn_s_barrier();
        __builtin_amdgcn_sched_barrier(0);
        // all waves' reads of buf done -> safe to overwrite with tile t+2
        if (t + 2 < NT) { STAGE_A(buf, t + 2); STAGE_B_LO(buf, t + 2); }
        __builtin_amdgcn_s_setprio(1);
#pragma unroll
        for (int tm = 0; tm < 6; ++tm)
#pragma unroll
            for (int tn = 0; tn < 4; ++tn)
                acc[tm][tn] = __builtin_amdgcn_mfma_f32_16x16x32_bf16(
                    a1[tm], b1[tn], acc[tm][tn], 0, 0, 0);
        __builtin_amdgcn_s_setprio(0);
        if (t + 2 < NT) {
            asm volatile("s_waitcnt vmcnt(5)" ::: "memory");  // tile t+1 landed
        } else if (t + 1 < NT) {
            asm volatile("s_waitcnt vmcnt(0)" ::: "memory");  // tail drain
        }
        __builtin_amdgcn_sched_barrier(0);
        __builtin_amdgcn_s_barrier();
        __builtin_amdgcn_sched_barrier(0);
    }
#undef STAGE_A
#undef STAGE_B_LO
#undef STAGE_B_HI

    // epilogue: C/D layout col = lane&15, row = quad*4 + reg
#pragma unroll
    for (int tm = 0; tm < 6; ++tm) {
#pragma unroll
        for (int tn = 0; tn < 4; ++tn) {
            const int n = n0 + wc * 64 + tn * 16 + mrow;
#pragma unroll
            for (int reg = 0; reg < 4; ++reg) {
                const long m = m0 + wr * 96 + tm * 16 + quad * 4 + reg;
                float p = acc[tm][tn][reg];
                float c = C0[m * (long)ldc + n];
                c += bias[(int)((m / LL) & (CO - 1))];
                Out[m * (long)ldo + n] = c + p;
            }
        }
    }
}

// =====================================================================
// generic fp32 GEMM (accuracy-critical sxg op only now)
template <int BM, int BN, int BK, int TM, int TN, bool RELU, bool ADDC0, bool BIAS, bool STB16>
__global__ __launch_bounds__(256)
void gemm_k(const float* __restrict__ X, int ldx,
            const float* __restrict__ Bm, int ldb,
            const float* __restrict__ C0, int ldc,
            const float* __restrict__ bias,
            float* __restrict__ Out, int ldo,
            unsigned short* __restrict__ outb, int K, float alpha) {
    constexpr int TX = BN / TN;
    constexpr int LX = (BM * BK) / 256;
    constexpr int LB = (BN * BK) / 256;
    __shared__ float Xs[BK][BM + 4];
    __shared__ float Bs[BK][BN + 4];
    const int tid = threadIdx.x;
    const int tx = tid % TX, ty = tid / TX;
    const long m0 = (long)blockIdx.y * BM;
    const int n0 = blockIdx.x * BN;
    const int xr = tid / (BK / LX);
    const int xcc = (tid % (BK / LX)) * LX;
    const int br = tid / (BN / LB);
    const int bc = (tid % (BN / LB)) * LB;

    float acc[TM][TN];
#pragma unroll
    for (int i = 0; i < TM; ++i)
#pragma unroll
        for (int j = 0; j < TN; ++j) acc[i][j] = 0.f;

    const float* Xp = X + (m0 + xr) * (long)ldx + xcc;
    const float* Bp = Bm + (long)br * ldb + n0 + bc;

    for (int k0 = 0; k0 < K; k0 += BK) {
        if constexpr (LX == 4) {
            const float4 v = *(const float4*)Xp;
            Xs[xcc + 0][xr] = v.x; Xs[xcc + 1][xr] = v.y;
            Xs[xcc + 2][xr] = v.z; Xs[xcc + 3][xr] = v.w;
        } else {
            const float2 v = *(const float2*)Xp;
            Xs[xcc + 0][xr] = v.x; Xs[xcc + 1][xr] = v.y;
        }
        if constexpr (LB == 4) {
            *(float4*)&Bs[br][bc] = *(const float4*)Bp;
        } else {
            *(float2*)&Bs[br][bc] = *(const float2*)Bp;
        }
        __syncthreads();
#pragma unroll
        for (int kk = 0; kk < BK; ++kk) {
            float a[TM], b[TN];
#pragma unroll
            for (int i = 0; i < TM; ++i) a[i] = Xs[kk][ty * TM + i];
#pragma unroll
            for (int j = 0; j < TN; ++j) b[j] = Bs[kk][tx * TN + j];
#pragma unroll
            for (int i = 0; i < TM; ++i)
#pragma unroll
                for (int j = 0; j < TN; ++j) acc[i][j] = fmaf(a[i], b[j], acc[i][j]);
        }
        __syncthreads();
        Xp += BK;
        Bp += (long)BK * ldb;
    }

#pragma unroll
    for (int i = 0; i < TM; ++i) {
        const long m = m0 + (long)ty * TM + i;
        float bv = 0.f;
        if (BIAS) bv = bias[(int)((m / LL) & (CO - 1))];
        const long obase = m * (long)ldo + n0 + tx * TN;
        long cbase = 0;
        if constexpr (ADDC0) cbase = m * (long)ldc + n0 + tx * TN;
#pragma unroll
        for (int j = 0; j < TN; ++j) {
            float p = acc[i][j];
            if (RELU) p = fmaxf(p, 0.f);
            p *= alpha;
            float c = 0.f;
            if constexpr (ADDC0) c = C0[cbase + j];
            const float res = c + p + bv;
            Out[obase + j] = res;
            if constexpr (STB16) outb[obase + j] = f2bf(res);
        }
    }
}

// =====================================================================
__global__ __launch_bounds__(256)
void zero_k(float* __restrict__ p, int n) {
    for (int i = blockIdx.x * 256 + threadIdx.x; i < n; i += gridDim.x * 256) p[i] = 0.f;
}

// split-K Gram with mismatched flatten orders (faithful)
__global__ __launch_bounds__(256)
void asmat_split(const float* __restrict__ sxg, float* __restrict__ am_raw) {
    __shared__ float Us[128][65];
    __shared__ float Wsh[128][65];
    __shared__ int rA[128], rB[128];
    const int i0 = blockIdx.x * 128;
    const int tid = threadIdx.x;
    if (tid < 128) {
        const int i = i0 + tid;
        const int c = i / 192;
        const int rem = i - c * 192;
        const int n = rem / 12;
        const int l = rem - n * 12;
        rA[tid] = (n * 32 + c) * 12 + l;
        const int l2 = i >> 9;
        const int rem2 = i & 511;
        rB[tid] = ((rem2 >> 5) * 32 + (rem2 & 31)) * 12 + l2;
    }
    __syncthreads();
    for (int idx = tid; idx < 128 * 64; idx += 256) {
        const int r = idx >> 6, s = idx & 63;
        Us[r][s] = sxg[rA[r] * 64 + s];
        Wsh[r][s] = sxg[rB[r] * 64 + s];
    }
    __syncthreads();
    const int ts = (tid & 15) * 4;
    const int tt = (tid >> 4) * 4;
    float acc[4][4];
#pragma unroll
    for (int i2 = 0; i2 < 4; ++i2)
#pragma unroll
        for (int j = 0; j < 4; ++j) acc[i2][j] = 0.f;
    for (int k = 0; k < 128; ++k) {
        float a[4], bv[4];
#pragma unroll
        for (int i2 = 0; i2 < 4; ++i2) a[i2] = Us[k][ts + i2];
#pragma unroll
        for (int j = 0; j < 4; ++j) bv[j] = Wsh[k][tt + j];
#pragma unroll
        for (int i2 = 0; i2 < 4; ++i2)
#pragma unroll
            for (int j = 0; j < 4; ++j) acc[i2][j] = fmaf(a[i2], bv[j], acc[i2][j]);
    }
#pragma unroll
    for (int i2 = 0; i2 < 4; ++i2)
#pragma unroll
        for (int j = 0; j < 4; ++j)
            atomicAdd(&am_raw[(ts + i2) * 64 + tt + j], acc[i2][j]);
}

// sup[0] = softmax(rownorm(relu(raw-0.5))), sup[1] = same on transpose
__global__ __launch_bounds__(64)
void supbuild_k(const float* __restrict__ am_raw, float* __restrict__ sup) {
    __shared__ float a[64][65];
    for (int idx = threadIdx.x; idx < 4096; idx += 64) {
        const float v = am_raw[idx] - 0.5f;
        a[idx >> 6][idx & 63] = v > 0.f ? v : 0.f;
    }
    __syncthreads();
    const int r = threadIdx.x;
    {
        float rs = 0.f;
        for (int j = 0; j < 64; ++j) rs += a[r][j];
        const float dinv = rs > 0.f ? 1.f / rs : 0.f;
        float mx = -1e30f;
        for (int j = 0; j < 64; ++j) mx = fmaxf(mx, a[r][j] * dinv);
        float se = 0.f;
        for (int j = 0; j < 64; ++j) se += expf(a[r][j] * dinv - mx);
        const float inv = 1.f / se;
        for (int j = 0; j < 64; ++j) sup[r * 64 + j] = expf(a[r][j] * dinv - mx) * inv;
    }
    {
        float rs = 0.f;
        for (int j = 0; j < 64; ++j) rs += a[j][r];
        const float dinv = rs > 0.f ? 1.f / rs : 0.f;
        float mx = -1e30f;
        for (int j = 0; j < 64; ++j) mx = fmaxf(mx, a[j][r] * dinv);
        float se = 0.f;
        for (int j = 0; j < 64; ++j) se += expf(a[j][r] * dinv - mx);
        const float inv = 1.f / se;
        for (int j = 0; j < 64; ++j) sup[4096 + r * 64 + j] = expf(a[j][r] * dinv - mx) * inv;
    }
}

// =====================================================================
extern "C" void kernel_launch(void* const* d_in, const int* in_sizes, int n_in,
                              void* d_out, int out_size, void* d_ws, size_t ws_size,
                              hipStream_t stream) {
    (void)in_sizes; (void)n_in; (void)out_size; (void)ws_size;
    const float* x    = (const float*)d_in[0];
    const float* sup  = (const float*)d_in[1];  // [2, V, V]
    const float* supc = (const float*)d_in[2];  // [2, VC, VC]
    const float* acs  = (const float*)d_in[3];  // [VC, S]
    const float* afc  = (const float*)d_in[4];  // [V, VC]
    const float* W    = (const float*)d_in[5];  // [32, 96]
    const float* b    = (const float*)d_in[6];  // [32]
    float* ws = (float*)d_ws;

    // --- region A [0, 12,582,912): xt fp32 (alive steps 1-4); then reused.
    // ALL bf16 conversions into this region run AFTER step 4 (round-9
    // lesson: a step-2b write here corrupted live xt -> absmax 0.78).
    float* xt = ws;
    unsigned short* Btu = (unsigned short*)ws;                // bf16 [2048][4096], step 5
    float* yc0  = ws + 4456448;
    unsigned short* yc12b = (unsigned short*)(ws + 6029312);  // bf16 [6144][512]
    unsigned short* supcTb = (unsigned short*)(ws + 7602176); // bf16 [256][512], step 5a
    float* ys0  = ws + 9175040;
    unsigned short* ysb = (unsigned short*)(ws + 9568256);    // bf16 [6144][128] (old ys12)
    float* hc   = ws + 10354688;
    float* hs   = ws + 11927552;
    float* am   = ws + 12320768;
    float* sups = ws + 12324864;
    unsigned short* acsb   = (unsigned short*)(ws + 12333056); // bf16 [256][64], step 5b
    unsigned short* acsTb  = (unsigned short*)(ws + 12341248); // bf16 [64][256], step 5b
    unsigned short* supsTb = (unsigned short*)(ws + 12349440); // bf16 [64][128], step 9.5
    // --- fixed regions
    float* hf   = ws + 12582912;                              // y0 then hf
    float* xc   = ws + 25165824;
    float* sxg  = ws + 26738688;
    unsigned short* afcTb = (unsigned short*)(ws + 27131904); // bf16 [256][2048]
    unsigned short* afcb  = (unsigned short*)(ws + 27394048); // bf16 [2048][256]
    // ws total 27,656,192 floats (~110.6 MB)

    // --- d_out doubles as scratch (dead before final output writes)
    float* out_f = (float*)d_out;
    unsigned short* xtb  = (unsigned short*)d_out;            // bf16 [6144][2048], steps 1-3
    unsigned short* y12u = (unsigned short*)d_out;            // bf16 [6144][4096], steps 4-10
    unsigned short* hfb  = (unsigned short*)d_out;            // bf16 [6144][2048], steps 15-16
    unsigned short* hcb  = ((unsigned short*)d_out) + 12582912;  // bf16 [6144][256], 14-17
    unsigned short* hsb  = ((unsigned short*)d_out) + 14155776;  // bf16 [6144][64], 12-14
    float* hf_out = out_f;
    float* hc_out = out_f + 12582912;
    float* hs_out = out_f + 14155776;

    // 1. xt = transpose(x) (+ bf16 copy xtb into d_out)
    transpose_vl<<<dim3(VV / 128, NB * CC), 256, 0, stream>>>(x, xt, xtb);
    // 2. afcb + afcTb in one pass (ws tail - outside xt region)
    cvt_afc_both<<<dim3(VCC / 32, VV / 32), 256, 0, stream>>>(afc, afcb, afcTb);
    // 3. xc = xtb @ afc  (MFMA BN=64; B^T = afcTb)
    gemm_mfma<64, false, false, false, false, false><<<dim3(VCC / 64, MM / 128), 256, 0, stream>>>(
        xtb, VV, afcTb, VV, nullptr, 0, nullptr, xc, VCC, nullptr, VV, 1.0f);
    // 4. fine chanmix: y0 -> hf (fp32), y12 -> d_out (bf16; clobbers xtb - dead)
    chanmix_fine<<<dim3(96, 16), 256, 0, stream>>>(xt, W, hf, y12u);
    // ---- xt dead from here; region-A conversions now safe ----
    // 5a. supcTb = bf16([Ac1;Ac2]^T) [256][512]
    cvt_T_bf16_k<<<dim3(VCC / 32, 2 * VCC / 32), 256, 0, stream>>>(supc, supcTb, 2 * VCC, VCC);
    // 5b. acsb = bf16(acs) [256][64]; acsTb = bf16(acs^T) [64][256]
    cvt_bf16_k<<<dim3(16), 256, 0, stream>>>(acs, acsb, VCC * SS);
    cvt_T_bf16_k<<<dim3(SS / 32, VCC / 32), 256, 0, stream>>>(acs, acsTb, VCC, SS);
    // 5. Btu = bf16([A1;A2]^T) [2048][4096]
    cvt_T_bf16_k<<<dim3(VV / 32, 2 * VV / 32), 256, 0, stream>>>(sup, Btu, 2 * VV, VV);
    // 6. sxg = xc @ acs (fp32 - feeds threshold-sensitive Gram; keep fp32)
    gemm_k<32, 64, 16, 2, 4, false, false, false, false><<<dim3(1, MM / 32), 256, 0, stream>>>(
        xc, VCC, acs, SS, nullptr, 0, nullptr, sxg, SS, nullptr, VCC, 1.0f);
    // 7. coarse chanmix: yc0 fp32 + yc12b bf16
    chanmix_k<false, true><<<dim3(12, 16), 256, 0, stream>>>(
        xc, W, LL * VCC, VCC, yc0, nullptr, yc12b, 2 * VCC);
    // 8. super chanmix: ys0 fp32 + ysb bf16 (step 12 now MFMA)
    chanmix_k<false, true><<<dim3(3, 16), 256, 0, stream>>>(
        sxg, W, LL * SS, SS, ys0, nullptr, ysb, 2 * SS);
    // 9. gram + supports (fp32, faithful)
    zero_k<<<dim3(4), 256, 0, stream>>>(am, 4096);
    asmat_split<<<dim3(48), 256, 0, stream>>>(sxg, am);
    supbuild_k<<<dim3(1), 64, 0, stream>>>(am, sups);
    // 9.5. supsTb = bf16([As1;As2]^T) [64][128]
    cvt_T_bf16_k<<<dim3(SS / 32, 2 * SS / 32), 256, 0, stream>>>(sups, supsTb, 2 * SS, SS);
    // 10. K3 (192x256 8-wave counted-vmcnt MFMA): hf = y0 + y12 @ [A1;A2] + bias
    gemm_mfma256<<<dim3(VV / 256, MM / 192), 512, 0, stream>>>(
        y12u, 4096, Btu, 4096, hf, VV, b, hf, VV, 4096);
    // 11. hc = yc0 + yc12 @ [Ac1;Ac2] + bias (bf16 MFMA, K=512)
    gemm_mfma<64, false, false, true, true, false><<<dim3(VCC / 64, MM / 128), 256, 0, stream>>>(
        yc12b, 2 * VCC, supcTb, 2 * VCC, yc0, VCC, b, hc, VCC, nullptr, 2 * VCC, 1.0f);
    // 12. hs = ys0 + ys12 @ [As1;As2] + bias (bf16 MFMA, K=128; dual-store hsb)
    gemm_mfma<64, false, false, true, true, true><<<dim3(1, MM / 128), 256, 0, stream>>>(
        ysb, 2 * SS, supsTb, 2 * SS, ys0, SS, b, hs, SS, hsb, 2 * SS, 1.0f);
    // 14. hc += 0.8 * relu(hs @ acs^T) (bf16 MFMA, K=64; Bt = acs directly);
    //     dual-store hcb
    gemm_mfma<64, false, true, true, false, true><<<dim3(VCC / 64, MM / 128), 256, 0, stream>>>(
        hsb, SS, acsb, SS, hc, VCC, nullptr, hc, VCC, hcb, SS, 0.8f);
    // 15. hf += 0.2 * relu(hcb @ afc^T) (MFMA, swizzle), dual-store hfb bf16
    gemm_mfma<128, true, true, true, false, true><<<dim3(VV / 128, MM / 128), 256, 0, stream>>>(
        hcb, VCC, afcb, VCC, hf, VV, nullptr, hf, VV, hfb, VCC, 0.2f);
    // 16. hc += 0.2 * relu(hfb @ afc) (MFMA BN=64; B^T = afcTb); dual-store
    //     updated hcb (consumed by step 17)
    gemm_mfma<64, false, true, true, false, true><<<dim3(VCC / 64, MM / 128), 256, 0, stream>>>(
        hfb, VV, afcTb, VV, hc, VCC, nullptr, hc, VCC, hcb, VV, 0.2f);
    // 17. hs += 0.2 * relu(hc @ acs) (bf16 MFMA, K=256; Bt = acsTb)
    gemm_mfma<64, false, true, true, false, false><<<dim3(1, MM / 128), 256, 0, stream>>>(
        hcb, VCC, acsTb, VCC, hs, SS, nullptr, hs, SS, nullptr, VCC, 0.2f);
    // 18. node-last -> reference layout [*, node, L]
    transpose_lv<<<dim3(VV / 128, NB * CO), 256, 0, stream>>>(hf, hf_out, VV, 128);
    transpose_lv<<<dim3(VCC / 128, NB * CO), 256, 0, stream>>>(hc, hc_out, VCC, 128);
    transpose_lv<<<dim3(1, NB * CO), 256, 0, stream>>>(hs, hs_out, SS, 64);
}